// Round 10
// baseline (348.628 us; speedup 1.0000x reference)
//
#include <hip/hip_runtime.h>

typedef unsigned short u16;
typedef __attribute__((ext_vector_type(8))) __bf16 bf16x8;
typedef __attribute__((ext_vector_type(4))) __bf16 bf16x4;
typedef __attribute__((ext_vector_type(4))) float f32x4;
typedef __attribute__((ext_vector_type(4))) unsigned short u16x4;

#define AS1 __attribute__((address_space(1)))
#define AS3 __attribute__((address_space(3)))

__device__ __forceinline__ void async_load16(const void* g, void* l) {
  __builtin_amdgcn_global_load_lds((const AS1 void*)g, (AS3 void*)l, 16, 0, 0);
}

__device__ __forceinline__ float exp2_fast(float x) {
#if __has_builtin(__builtin_amdgcn_exp2f)
  return __builtin_amdgcn_exp2f(x);
#else
  return exp2f(x);
#endif
}
__device__ __forceinline__ float rcp_fast(float x) {
#if __has_builtin(__builtin_amdgcn_rcpf)
  return __builtin_amdgcn_rcpf(x);
#else
  return 1.0f / x;
#endif
}

__device__ __forceinline__ u16 f2bf(float f) {   // manual RNE
  union { float f; unsigned u; } a; a.f = f;
  unsigned u = a.u;
  u += 0x7fffu + ((u >> 16) & 1u);
  return (u16)(u >> 16);
}
__device__ __forceinline__ u16 bf_bits(float f) {  // native cvt (RNE)
  union { __bf16 b; u16 u; } c; c.b = (__bf16)f; return c.u;
}
__device__ __forceinline__ float bf2f(u16 h) {
  union { unsigned u; float f; } c; c.u = ((unsigned)h) << 16; return c.f;
}

// ------- fp32 -> bf16: all 6 weights in ONE launch (dst contiguous in ws) -------
__global__ __launch_bounds__(256)
void f2b_all(const float* __restrict__ s0, const float* __restrict__ s1,
             const float* __restrict__ s2, const float* __restrict__ s3,
             const float* __restrict__ s4, const float* __restrict__ s5,
             u16* __restrict__ dst) {
  const int i = blockIdx.x * 256 + threadIdx.x;   // < 3145728
  const float* s; int off;
  if (i < 1048576) {
    if (i < 262144)      { s = s0; off = i; }
    else if (i < 524288) { s = s1; off = i - 262144; }
    else if (i < 786432) { s = s2; off = i - 524288; }
    else                 { s = s3; off = i - 786432; }
  } else if (i < 2097152) { s = s4; off = i - 1048576; }
  else                    { s = s5; off = i - 2097152; }
  const float4 v = ((const float4*)s)[off];
  u16x4 o; o[0] = f2bf(v.x); o[1] = f2bf(v.y); o[2] = f2bf(v.z); o[3] = f2bf(v.w);
  ((u16x4*)dst)[i] = o;
}

// ---------------- LayerNorm (1024 cols, 1 block/row) ----------------
__global__ __launch_bounds__(256)
void ln_kernel(const float* __restrict__ x, const float* __restrict__ g,
               const float* __restrict__ b, u16* __restrict__ out) {
  const int row = blockIdx.x, tid = threadIdx.x;
  const float4 v = ((const float4*)(x + (size_t)row * 1024))[tid];
  float s = v.x + v.y + v.z + v.w;
  float s2 = v.x * v.x + v.y * v.y + v.z * v.z + v.w * v.w;
#pragma unroll
  for (int o = 1; o < 64; o <<= 1) { s += __shfl_xor(s, o); s2 += __shfl_xor(s2, o); }
  __shared__ float red[8];
  const int wave = tid >> 6, lane = tid & 63;
  if (lane == 0) { red[wave] = s; red[wave + 4] = s2; }
  __syncthreads();
  s = red[0] + red[1] + red[2] + red[3];
  s2 = red[4] + red[5] + red[6] + red[7];
  const float mu = s * (1.f / 1024.f);
  const float rstd = rsqrtf(s2 * (1.f / 1024.f) - mu * mu + 1e-5f);
  const float4 gg = ((const float4*)g)[tid];
  const float4 bb = ((const float4*)b)[tid];
  u16x4 o4;
  o4[0] = f2bf((v.x - mu) * rstd * gg.x + bb.x);
  o4[1] = f2bf((v.y - mu) * rstd * gg.y + bb.y);
  o4[2] = f2bf((v.z - mu) * rstd * gg.z + bb.z);
  o4[3] = f2bf((v.w - mu) * rstd * gg.w + bb.w);
  ((u16x4*)(out + (size_t)row * 1024))[tid] = o4;
}

// -- fused: out = x + p[0] + p[1] + bo (bf16 partials); hb = LN(out; g,b) --
__global__ __launch_bounds__(256)
void ln_fuse(const float* __restrict__ x, const u16* __restrict__ parts,
             const float* __restrict__ bo, const float* __restrict__ g,
             const float* __restrict__ b, float* __restrict__ out,
             u16* __restrict__ hb) {
  const int row = blockIdx.x, tid = threadIdx.x;
  const size_t base = (size_t)row * 1024;
  const int i4 = row * 256 + tid;
  const float4 xv = ((const float4*)(x + base))[tid];
  const u16x4 h0 = ((const u16x4*)parts)[i4];
  const u16x4 h1 = ((const u16x4*)(parts + 4194304))[i4];
  const float4 bv = ((const float4*)bo)[tid];
  float4 t;
  t.x = xv.x + bf2f(h0[0]) + bf2f(h1[0]) + bv.x;
  t.y = xv.y + bf2f(h0[1]) + bf2f(h1[1]) + bv.y;
  t.z = xv.z + bf2f(h0[2]) + bf2f(h1[2]) + bv.z;
  t.w = xv.w + bf2f(h0[3]) + bf2f(h1[3]) + bv.w;
  ((float4*)(out + base))[tid] = t;
  float s = t.x + t.y + t.z + t.w;
  float s2 = t.x * t.x + t.y * t.y + t.z * t.z + t.w * t.w;
#pragma unroll
  for (int o = 1; o < 64; o <<= 1) { s += __shfl_xor(s, o); s2 += __shfl_xor(s2, o); }
  __shared__ float red[8];
  const int wave = tid >> 6, lane = tid & 63;
  if (lane == 0) { red[wave] = s; red[wave + 4] = s2; }
  __syncthreads();
  s = red[0] + red[1] + red[2] + red[3];
  s2 = red[4] + red[5] + red[6] + red[7];
  const float mu = s * (1.f / 1024.f);
  const float rstd = rsqrtf(s2 * (1.f / 1024.f) - mu * mu + 1e-5f);
  const float4 gg = ((const float4*)g)[tid];
  const float4 bb = ((const float4*)b)[tid];
  u16x4 o4;
  o4[0] = f2bf((t.x - mu) * rstd * gg.x + bb.x);
  o4[1] = f2bf((t.y - mu) * rstd * gg.y + bb.y);
  o4[2] = f2bf((t.z - mu) * rstd * gg.z + bb.z);
  o4[3] = f2bf((t.w - mu) * rstd * gg.w + bb.w);
  ((u16x4*)(hb + base))[tid] = o4;
}

// ------- out += p[0..3] + b2 (MLP2 reduction over 4 bf16 partial slices) -------
__global__ __launch_bounds__(256)
void add4(float* __restrict__ out, const u16* __restrict__ p,
          const float* __restrict__ b2) {
  const int i = blockIdx.x * 256 + threadIdx.x;   // f4 index < 1048576
  const float4 o = ((const float4*)out)[i];
  const float4 bv = ((const float4*)b2)[i & 255];
  float a0 = o.x + bv.x, a1 = o.y + bv.y, a2 = o.z + bv.z, a3 = o.w + bv.w;
#pragma unroll
  for (int kz = 0; kz < 4; kz++) {
    const u16x4 h = ((const u16x4*)(p + (size_t)kz * 4194304))[i];
    a0 += bf2f(h[0]); a1 += bf2f(h[1]); a2 += bf2f(h[2]); a3 += bf2f(h[3]);
  }
  float4 r; r.x = a0; r.y = a1; r.z = a2; r.w = a3;
  ((float4*)out)[i] = r;
}

// ---------------- GEMM C = A * B^T, A[M,ldk] bf16, B[N,ldk] bf16 ----------------
// BM=BN=128, BK=64; 4 waves in 2x2, wave tile 64x64 (acc 4x4 in AGPR).
// DOUBLE-BUFFERED LDS (2 x 32KB = 64KB), ONE barrier per K-iter: next tile's
// global_load_lds issued BEFORE compute of current tile; __syncthreads' implicit
// vmcnt(0) drain then waits only (latency - compute), not full latency (R9
// counters: issue->sync->compute serialization was the 21% MfmaUtil cause).
// m201 st_16x32 swizzle (chunk-bit1 ^= row-bit2) via pre-swizzled global src
// (LDS dest wave-uniform linear, m104/m108). M fixed 4096 -> 32 m-blocks;
// grid id = mb + 32*(nb + NB*kz).
template <class Epi>
__global__ __launch_bounds__(256, 2)
void gemm_bt(const u16* __restrict__ A, const u16* __restrict__ Bw,
             int ldk, int K, int NB, Epi epi) {
  __shared__ __align__(16) u16 As[2][128 * 64];   // 2 x 16 KB
  __shared__ __align__(16) u16 Bs[2][128 * 64];   // 2 x 16 KB
  const int tid = threadIdx.x;
  const int wave = tid >> 6, lane = tid & 63;
  const int quad = lane >> 4, l16 = lane & 15;
  const int wr = wave >> 1, wc = wave & 1;
  const int id = blockIdx.x;
  const int mb = id & 31;
  const int t = id >> 5;
  const int nb = t % NB;
  const int kz = t / NB;
  const int bm = mb * 128, bn = nb * 128;

  const int rowg = wave * 8 + (lane >> 3);    // 0..31 row within a 32-row slab
  const int chunk = lane & 7;                 // 16B chunk slot this lane fills
  const int scol = (chunk ^ (2 * ((rowg >> 2) & 1))) * 8;  // inverse-swizzled src
  const u16* pa[4];
  const u16* pb[4];
#pragma unroll
  for (int j = 0; j < 4; j++) {               // slab j covers rows j*32..j*32+31
    pa[j] = A + (size_t)(bm + j * 32 + rowg) * ldk + (size_t)kz * K + scol;
    pb[j] = Bw + (size_t)(bn + j * 32 + rowg) * ldk + (size_t)kz * K + scol;
  }
  const int ldst = wave * 512;                // wave-uniform dest offset in slab

  const f32x4 fz = {0.f, 0.f, 0.f, 0.f};
  f32x4 acc[4][4];
#pragma unroll
  for (int i = 0; i < 4; i++)
#pragma unroll
    for (int j = 0; j < 4; j++) acc[i][j] = fz;

  const int qsw = (quad ^ (2 * ((l16 >> 2) & 1))) * 8;  // swizzled 16B slot

  // prologue: tile 0 into buffer 0
#pragma unroll
  for (int j = 0; j < 4; j++) { async_load16(pa[j], &As[0][j * 2048 + ldst]); pa[j] += 64; }
#pragma unroll
  for (int j = 0; j < 4; j++) { async_load16(pb[j], &Bs[0][j * 2048 + ldst]); pb[j] += 64; }
  __syncthreads();                            // vmcnt(0) drain: tile 0 ready

  const int niter = K >> 6;
  for (int i = 0; i < niter; i++) {
    const int cur = i & 1, nxt = cur ^ 1;
    if (i + 1 < niter) {                      // issue NEXT tile before compute
#pragma unroll
      for (int j = 0; j < 4; j++) { async_load16(pa[j], &As[nxt][j * 2048 + ldst]); pa[j] += 64; }
#pragma unroll
      for (int j = 0; j < 4; j++) { async_load16(pb[j], &Bs[nxt][j * 2048 + ldst]); pb[j] += 64; }
    }
#pragma unroll
    for (int kk = 0; kk < 2; kk++) {
      const int slot = qsw + kk * 32;
      bf16x8 af[4], bfr[4];
#pragma unroll
      for (int mi = 0; mi < 4; mi++)
        af[mi] = *(const bf16x8*)&As[cur][(wr * 64 + mi * 16 + l16) * 64 + slot];
#pragma unroll
      for (int ni = 0; ni < 4; ni++)
        bfr[ni] = *(const bf16x8*)&Bs[cur][(wc * 64 + ni * 16 + l16) * 64 + slot];
#pragma unroll
      for (int mi = 0; mi < 4; mi++)
#pragma unroll
        for (int ni = 0; ni < 4; ni++)
          acc[mi][ni] = __builtin_amdgcn_mfma_f32_16x16x32_bf16(af[mi], bfr[ni], acc[mi][ni], 0, 0, 0);
    }
    __syncthreads();   // drains vmcnt: next tile ready; WAR-safe for buffer reuse
  }
#pragma unroll
  for (int mi = 0; mi < 4; mi++)
#pragma unroll
    for (int ni = 0; ni < 4; ni++)
      epi(bm + wr * 64 + mi * 16 + quad * 4, bn + wc * 64 + ni * 16 + l16, kz, acc[mi][ni]);
}

// ---------------- epilogues (rows m0..m0+3, col n) ----------------
struct EpiQKV {   // q[b,h,s,e] scaled by 0.125*log2(e); k[b,h,s,e]; v^T[b,h,e,s]
  u16 *q, *k, *vt; const float *bq, *bk, *bv;
  __device__ void operator()(int m0, int n, int, f32x4 v) const {
    const int which = n >> 10, nn = n & 1023;
    const int hh = nn >> 6, e = nn & 63;
    const int bb = m0 >> 11, s0 = m0 & 2047;
    const size_t bh = (size_t)(bb * 16 + hh);
    if (which == 0) {
      const float bias = bq[nn];
      u16* p = &q[(bh * 2048 + s0) * 64 + e];
#pragma unroll
      for (int r = 0; r < 4; r++) p[r * 64] = bf_bits((v[r] + bias) * 0.18033688f);
    } else if (which == 1) {
      const float bias = bk[nn];
      u16* p = &k[(bh * 2048 + s0) * 64 + e];
#pragma unroll
      for (int r = 0; r < 4; r++) p[r * 64] = bf_bits(v[r] + bias);
    } else {
      const float bias = bv[nn];
      bf16x4 pk;
#pragma unroll
      for (int r = 0; r < 4; r++) pk[r] = (__bf16)(v[r] + bias);
      *(bf16x4*)&vt[(bh * 64 + e) * 2048 + s0] = pk;
    }
  }
};
struct EpiPartB {  // bf16 split-K partial -> p + kz*4194304  ([4096,1024] bf16)
  u16* p;
  __device__ void operator()(int m0, int n, int kz, f32x4 v) const {
    u16* pp = p + (size_t)kz * 4194304;
#pragma unroll
    for (int r = 0; r < 4; r++) pp[(size_t)(m0 + r) * 1024 + n] = bf_bits(v[r]);
  }
};
struct EpiGelu {  // gelu(u) = u * sigmoid(2*c*(u+0.044715u^3)) via exp2
  const float* b1; u16* o;
  __device__ void operator()(int m0, int n, int, f32x4 v) const {
    const float bias = b1[n];
#pragma unroll
    for (int r = 0; r < 4; r++) {
      const float u = v[r] + bias;
      const float z2 = u * (2.3021183f + 0.10294515f * u * u);
      const float d = 1.0f + exp2_fast(-z2);
      o[(size_t)(m0 + r) * 4096 + n] = bf_bits(u * rcp_fast(d));
    }
  }
};

// ---------------- flash attention, no-max softmax, KVBLK=128, 1 wave = 32 q-rows ----
// K LDS rows permuted (row u holds K[kv = 8*(u&15)+(u>>4)]) so the P tile lands
// in true-kv order as contiguous bf16x8 stores; V^T staged unpermuted.
__global__ __launch_bounds__(256)
void attn_kernel(const u16* __restrict__ Q, const u16* __restrict__ K,
                 const u16* __restrict__ Vt, u16* __restrict__ O) {
  __shared__ __align__(16) u16 Ks[128 * 72];    // 18.4 KB (K rows, 64 d + pad)
  __shared__ __align__(16) u16 Vs[64 * 136];    // 17.4 KB (e rows, 128 s + pad)
  __shared__ __align__(16) u16 Ps[4][32 * 136]; // 34.8 KB (per-wave P tiles)
  const int tid = threadIdx.x, wave = tid >> 6, lane = tid & 63;
  const int quad = lane >> 4, l16 = lane & 15;
  const int b = blockIdx.z, h = blockIdx.y, qt = blockIdx.x;
  const size_t bh = (size_t)(b * 16 + h);
  const u16* Qp = Q + bh * (size_t)(2048 * 64);
  const u16* Kp = K + bh * (size_t)(2048 * 64);
  const u16* Vp = Vt + bh * (size_t)(64 * 2048);
  const int q0 = qt * 128 + wave * 32;

  bf16x8 qf[2][2];
#pragma unroll
  for (int rg = 0; rg < 2; rg++) {
    const u16* qrow = &Qp[(size_t)(q0 + rg * 16 + l16) * 64 + quad * 8];
    qf[rg][0] = *(const bf16x8*)qrow;
    qf[rg][1] = *(const bf16x8*)(qrow + 32);
  }

  // K staging: 128 rows x 64 d / 256 thr = 32 u16/thr (half a row)
  const int srK = tid >> 1, scK = (tid & 1) * 32;
  const int krow = 8 * (srK & 15) + (srK >> 4);        // permuted key row
  const u16* kg = &Kp[(size_t)krow * 64 + scK];
  u16* kl = &Ks[srK * 72 + scK];
  // V staging: 64 e-rows x 128 s / 256 thr = 32 u16/thr
  const int srV = tid >> 2, scV = (tid & 3) * 32;
  const u16* vg = &Vp[(size_t)srV * 2048 + scV];
  u16* vl = &Vs[srV * 136 + scV];
  u16* Pw = &Ps[wave][0];

  bf16x8 ones;
#pragma unroll
  for (int i = 0; i < 8; i++) ones[i] = (__bf16)1.0f;

  const f32x4 fz = {0.f, 0.f, 0.f, 0.f};
  f32x4 acc[2][4], lsum[2];
#pragma unroll
  for (int rg = 0; rg < 2; rg++) {
    lsum[rg] = fz;
#pragma unroll
    for (int g = 0; g < 4; g++) acc[rg][g] = fz;
  }

  bf16x8 pk[4], pv[4];
#pragma unroll
  for (int c = 0; c < 4; c++) {
    pk[c] = *(const bf16x8*)(kg + 8 * c);
    pv[c] = *(const bf16x8*)(vg + 8 * c);
  }

  for (int t0 = 0; t0 < 2048; t0 += 128) {
#pragma unroll
    for (int c = 0; c < 4; c++) {
      *(bf16x8*)(kl + 8 * c) = pk[c];
      *(bf16x8*)(vl + 8 * c) = pv[c];
    }
    __syncthreads();
    kg += 128 * 64; vg += 128;
#pragma unroll
    for (int c = 0; c < 4; c++) {        // over-reads 1 tile past end: lands in
      pk[c] = *(const bf16x8*)(kg + 8 * c);   // the next ws buffer, unused
      pv[c] = *(const bf16x8*)(vg + 8 * c);
    }

    // ---- QK^T, first half (kv tiles g 0..3) ----
    f32x4 s[2][4];
    __builtin_amdgcn_s_setprio(1);
#pragma unroll
    for (int g = 0; g < 4; g++) {
      const u16* kr = &Ks[(g * 16 + l16) * 72 + quad * 8];
      const bf16x8 kb0 = *(const bf16x8*)kr;
      const bf16x8 kb1 = *(const bf16x8*)(kr + 32);
#pragma unroll
      for (int rg = 0; rg < 2; rg++) {
        f32x4 z = __builtin_amdgcn_mfma_f32_16x16x32_bf16(qf[rg][0], kb0, fz, 0, 0, 0);
        s[rg][g] = __builtin_amdgcn_mfma_f32_16x16x32_bf16(qf[rg][1], kb1, z, 0, 0, 0);
      }
    }
    __builtin_amdgcn_s_setprio(0);
#pragma unroll
    for (int rg = 0; rg < 2; rg++)
#pragma unroll
      for (int r = 0; r < 4; r++) {
        f32x4 pf;
#pragma unroll
        for (int g = 0; g < 4; g++) pf[g] = exp2_fast(s[rg][g][r]);
        const bf16x4 pb = __builtin_convertvector(pf, bf16x4);
        *(bf16x4*)&Pw[(rg * 16 + quad * 4 + r) * 136 + 8 * l16] = pb;
      }
    // ---- QK^T, second half (kv tiles g 4..7) ----
    __builtin_amdgcn_s_setprio(1);
#pragma unroll
    for (int g = 0; g < 4; g++) {
      const u16* kr = &Ks[((g + 4) * 16 + l16) * 72 + quad * 8];
      const bf16x8 kb0 = *(const bf16x8*)kr;
      const bf16x8 kb1 = *(const bf16x8*)(kr + 32);
#pragma unroll
      for (int rg = 0; rg < 2; rg++) {
        f32x4 z = __builtin_amdgcn_mfma_f32_16x16x32_bf16(qf[rg][0], kb0, fz, 0, 0, 0);
        s[rg][g] = __builtin_amdgcn_mfma_f32_16x16x32_bf16(qf[rg][1], kb1, z, 0, 0, 0);
      }
    }
    __builtin_amdgcn_s_setprio(0);
#pragma unroll
    for (int rg = 0; rg < 2; rg++)
#pragma unroll
      for (int r = 0; r < 4; r++) {
        f32x4 pf;
#pragma unroll
        for (int g = 0; g < 4; g++) pf[g] = exp2_fast(s[rg][g][r]);
        const bf16x4 pb = __builtin_convertvector(pf, bf16x4);
        *(bf16x4*)&Pw[(rg * 16 + quad * 4 + r) * 136 + 8 * l16 + 4] = pb;
      }

    // ---- P readback (true kv order) + row-sum + PV ----
    bf16x8 pa[2][4];
#pragma unroll
    for (int rg = 0; rg < 2; rg++)
#pragma unroll
      for (int hh2 = 0; hh2 < 4; hh2++) {
        pa[rg][hh2] = *(const bf16x8*)&Pw[(rg * 16 + l16) * 136 + quad * 8 + hh2 * 32];
        lsum[rg] = __builtin_amdgcn_mfma_f32_16x16x32_bf16(pa[rg][hh2], ones, lsum[rg], 0, 0, 0);
      }
    __builtin_amdgcn_s_setprio(1);
#pragma unroll
    for (int g = 0; g < 4; g++) {
      const u16* vr = &Vs[(g * 16 + l16) * 136 + quad * 8];
#pragma unroll
      for (int hh2 = 0; hh2 < 4; hh2++) {
        const bf16x8 vb = *(const bf16x8*)(vr + hh2 * 32);
#pragma unroll
        for (int rg = 0; rg < 2; rg++)
          acc[rg][g] = __builtin_amdgcn_mfma_f32_16x16x32_bf16(pa[rg][hh2], vb, acc[rg][g], 0, 0, 0);
      }
    }
    __builtin_amdgcn_s_setprio(0);
    __syncthreads();
  }
#pragma unroll
  for (int rg = 0; rg < 2; rg++)
#pragma unroll
    for (int r = 0; r < 4; r++) {
      const float inv = rcp_fast(lsum[rg][r]);
      const int s_row = q0 + rg * 16 + quad * 4 + r;
      u16* op = (u16*)&O[((size_t)(b * 2048 + s_row)) * 1024 + h * 64 + l16];
#pragma unroll
      for (int g = 0; g < 4; g++) op[g * 16] = bf_bits(acc[rg][g][r] * inv);
    }
}

// ---------------- launch ----------------
extern "C" void kernel_launch(void* const* d_in, const int* in_sizes, int n_in,
                              void* d_out, int out_size, void* d_ws, size_t ws_size,
                              hipStream_t stream) {
  const float* x   = (const float*)d_in[0];
  const float* Wq  = (const float*)d_in[1];
  const float* bq  = (const float*)d_in[2];
  const float* Wk  = (const float*)d_in[3];
  const float* bk  = (const float*)d_in[4];
  const float* Wv  = (const float*)d_in[5];
  const float* bv  = (const float*)d_in[6];
  const float* Wo  = (const float*)d_in[7];
  const float* bo  = (const float*)d_in[8];
  const float* g1  = (const float*)d_in[9];
  const float* be1 = (const float*)d_in[10];
  const float* W1  = (const float*)d_in[11];
  const float* b1  = (const float*)d_in[12];
  const float* W2  = (const float*)d_in[13];
  const float* b2  = (const float*)d_in[14];
  const float* g2  = (const float*)d_in[15];
  const float* be2 = (const float*)d_in[16];
  float* out = (float*)d_out;

  char* w = (char*)d_ws;
  u16* wqkv = (u16*)w; w += (size_t)3072 * 1024 * 2;   // contiguous bf16 weights:
  u16* wob  = (u16*)w; w += (size_t)1024 * 1024 * 2;   //   wqkv|wob|w1b|w2b
  u16* w1b  = (u16*)w; w += (size_t)4096 * 1024 * 2;
  u16* w2b  = (u16*)w; w += (size_t)1024 * 4096 * 2;
  u16* hb   = (u16*)w; w += (size_t)4096 * 1024 * 2;
  u16* qb   = (u16*)w; w += (size_t)4096 * 1024 * 2;   // later: MLP2 partials (4x8MB
  u16* kb   = (u16*)w; w += (size_t)4096 * 1024 * 2;   //   bf16 spanning qb..atb)
  u16* vtb  = (u16*)w; w += (size_t)4096 * 1024 * 2;
  u16* atb  = (u16*)w; w += (size_t)4096 * 1024 * 2;
  u16* m1b  = (u16*)w; w += (size_t)4096 * 4096 * 2;   // O-proj partials first (2x8MB)

  u16* op_part = m1b;   // O-proj bf16 partials, dead before MLP1 writes m1b
  u16* ml_part = qb;    // MLP2 bf16 partials, qb..atb all dead after O-proj

  f2b_all<<<12288, 256, 0, stream>>>(Wq, Wk, Wv, Wo, W1, W2, wqkv);

  ln_kernel<<<4096, 256, 0, stream>>>(x, g1, be1, hb);
  // QKV: M=4096, N=3072, K=1024 -> grid 32*24 = 768
  gemm_bt<EpiQKV><<<768, 256, 0, stream>>>(hb, wqkv, 1024, 1024, 24,
      EpiQKV{qb, kb, vtb, bq, bk, bv});
  attn_kernel<<<dim3(16, 16, 2), 256, 0, stream>>>(qb, kb, vtb, atb);
  // O-proj: N=1024, K=1024 split 2 -> grid 32*8*2 = 512
  gemm_bt<EpiPartB><<<512, 256, 0, stream>>>(atb, wob, 1024, 512, 8,
      EpiPartB{op_part});
  ln_fuse<<<4096, 256, 0, stream>>>(x, op_part, bo, g2, be2, out, hb);
  // MLP1: N=4096, K=1024 -> grid 32*32 = 1024
  gemm_bt<EpiGelu><<<1024, 256, 0, stream>>>(hb, w1b, 1024, 1024, 32,
      EpiGelu{b1, m1b});
  // MLP2: N=1024, K=4096 split 4 -> grid 32*8*4 = 1024
  gemm_bt<EpiPartB><<<1024, 256, 0, stream>>>(m1b, w2b, 4096, 1024, 8,
      EpiPartB{ml_part});
  add4<<<4096, 256, 0, stream>>>(out, ml_part, b2);
}

// Round 12
// 341.367 us; speedup vs baseline: 1.0213x; 1.0213x over previous
//
#include <hip/hip_runtime.h>

typedef unsigned short u16;
typedef __attribute__((ext_vector_type(8))) __bf16 bf16x8;
typedef __attribute__((ext_vector_type(4))) __bf16 bf16x4;
typedef __attribute__((ext_vector_type(4))) float f32x4;
typedef __attribute__((ext_vector_type(4))) unsigned short u16x4;

#define AS1 __attribute__((address_space(1)))
#define AS3 __attribute__((address_space(3)))

__device__ __forceinline__ void async_load16(const void* g, void* l) {
  __builtin_amdgcn_global_load_lds((const AS1 void*)g, (AS3 void*)l, 16, 0, 0);
}

__device__ __forceinline__ float exp2_fast(float x) {
#if __has_builtin(__builtin_amdgcn_exp2f)
  return __builtin_amdgcn_exp2f(x);
#else
  return exp2f(x);
#endif
}
__device__ __forceinline__ float rcp_fast(float x) {
#if __has_builtin(__builtin_amdgcn_rcpf)
  return __builtin_amdgcn_rcpf(x);
#else
  return 1.0f / x;
#endif
}

__device__ __forceinline__ u16 f2bf(float f) {   // manual RNE
  union { float f; unsigned u; } a; a.f = f;
  unsigned u = a.u;
  u += 0x7fffu + ((u >> 16) & 1u);
  return (u16)(u >> 16);
}
__device__ __forceinline__ u16 bf_bits(float f) {  // native cvt (RNE)
  union { __bf16 b; u16 u; } c; c.b = (__bf16)f; return c.u;
}
__device__ __forceinline__ float bf2f(u16 h) {
  union { unsigned u; float f; } c; c.u = ((unsigned)h) << 16; return c.f;
}

// ------- fp32 -> bf16: all 6 weights in ONE launch (dst contiguous in ws) -------
__global__ __launch_bounds__(256)
void f2b_all(const float* __restrict__ s0, const float* __restrict__ s1,
             const float* __restrict__ s2, const float* __restrict__ s3,
             const float* __restrict__ s4, const float* __restrict__ s5,
             u16* __restrict__ dst) {
  const int i = blockIdx.x * 256 + threadIdx.x;   // < 3145728
  const float* s; int off;
  if (i < 1048576) {
    if (i < 262144)      { s = s0; off = i; }
    else if (i < 524288) { s = s1; off = i - 262144; }
    else if (i < 786432) { s = s2; off = i - 524288; }
    else                 { s = s3; off = i - 786432; }
  } else if (i < 2097152) { s = s4; off = i - 1048576; }
  else                    { s = s5; off = i - 2097152; }
  const float4 v = ((const float4*)s)[off];
  u16x4 o; o[0] = f2bf(v.x); o[1] = f2bf(v.y); o[2] = f2bf(v.z); o[3] = f2bf(v.w);
  ((u16x4*)dst)[i] = o;
}

// ---------------- LayerNorm (1024 cols, 1 block/row) ----------------
__global__ __launch_bounds__(256)
void ln_kernel(const float* __restrict__ x, const float* __restrict__ g,
               const float* __restrict__ b, u16* __restrict__ out) {
  const int row = blockIdx.x, tid = threadIdx.x;
  const float4 v = ((const float4*)(x + (size_t)row * 1024))[tid];
  float s = v.x + v.y + v.z + v.w;
  float s2 = v.x * v.x + v.y * v.y + v.z * v.z + v.w * v.w;
#pragma unroll
  for (int o = 1; o < 64; o <<= 1) { s += __shfl_xor(s, o); s2 += __shfl_xor(s2, o); }
  __shared__ float red[8];
  const int wave = tid >> 6, lane = tid & 63;
  if (lane == 0) { red[wave] = s; red[wave + 4] = s2; }
  __syncthreads();
  s = red[0] + red[1] + red[2] + red[3];
  s2 = red[4] + red[5] + red[6] + red[7];
  const float mu = s * (1.f / 1024.f);
  const float rstd = rsqrtf(s2 * (1.f / 1024.f) - mu * mu + 1e-5f);
  const float4 gg = ((const float4*)g)[tid];
  const float4 bb = ((const float4*)b)[tid];
  u16x4 o4;
  o4[0] = f2bf((v.x - mu) * rstd * gg.x + bb.x);
  o4[1] = f2bf((v.y - mu) * rstd * gg.y + bb.y);
  o4[2] = f2bf((v.z - mu) * rstd * gg.z + bb.z);
  o4[3] = f2bf((v.w - mu) * rstd * gg.w + bb.w);
  ((u16x4*)(out + (size_t)row * 1024))[tid] = o4;
}

// -- fused: out = x + p[0] + p[1] + bo (bf16 partials); hb = LN(out; g,b) --
__global__ __launch_bounds__(256)
void ln_fuse(const float* __restrict__ x, const u16* __restrict__ parts,
             const float* __restrict__ bo, const float* __restrict__ g,
             const float* __restrict__ b, float* __restrict__ out,
             u16* __restrict__ hb) {
  const int row = blockIdx.x, tid = threadIdx.x;
  const size_t base = (size_t)row * 1024;
  const int i4 = row * 256 + tid;
  const float4 xv = ((const float4*)(x + base))[tid];
  const u16x4 h0 = ((const u16x4*)parts)[i4];
  const u16x4 h1 = ((const u16x4*)(parts + 4194304))[i4];
  const float4 bv = ((const float4*)bo)[tid];
  float4 t;
  t.x = xv.x + bf2f(h0[0]) + bf2f(h1[0]) + bv.x;
  t.y = xv.y + bf2f(h0[1]) + bf2f(h1[1]) + bv.y;
  t.z = xv.z + bf2f(h0[2]) + bf2f(h1[2]) + bv.z;
  t.w = xv.w + bf2f(h0[3]) + bf2f(h1[3]) + bv.w;
  ((float4*)(out + base))[tid] = t;
  float s = t.x + t.y + t.z + t.w;
  float s2 = t.x * t.x + t.y * t.y + t.z * t.z + t.w * t.w;
#pragma unroll
  for (int o = 1; o < 64; o <<= 1) { s += __shfl_xor(s, o); s2 += __shfl_xor(s2, o); }
  __shared__ float red[8];
  const int wave = tid >> 6, lane = tid & 63;
  if (lane == 0) { red[wave] = s; red[wave + 4] = s2; }
  __syncthreads();
  s = red[0] + red[1] + red[2] + red[3];
  s2 = red[4] + red[5] + red[6] + red[7];
  const float mu = s * (1.f / 1024.f);
  const float rstd = rsqrtf(s2 * (1.f / 1024.f) - mu * mu + 1e-5f);
  const float4 gg = ((const float4*)g)[tid];
  const float4 bb = ((const float4*)b)[tid];
  u16x4 o4;
  o4[0] = f2bf((t.x - mu) * rstd * gg.x + bb.x);
  o4[1] = f2bf((t.y - mu) * rstd * gg.y + bb.y);
  o4[2] = f2bf((t.z - mu) * rstd * gg.z + bb.z);
  o4[3] = f2bf((t.w - mu) * rstd * gg.w + bb.w);
  ((u16x4*)(hb + base))[tid] = o4;
}

// ------- out += p[0..3] + b2 (MLP2 reduction over 4 bf16 partial slices) -------
__global__ __launch_bounds__(256)
void add4(float* __restrict__ out, const u16* __restrict__ p,
          const float* __restrict__ b2) {
  const int i = blockIdx.x * 256 + threadIdx.x;   // f4 index < 1048576
  const float4 o = ((const float4*)out)[i];
  const float4 bv = ((const float4*)b2)[i & 255];
  float a0 = o.x + bv.x, a1 = o.y + bv.y, a2 = o.z + bv.z, a3 = o.w + bv.w;
#pragma unroll
  for (int kz = 0; kz < 4; kz++) {
    const u16x4 h = ((const u16x4*)(p + (size_t)kz * 4194304))[i];
    a0 += bf2f(h[0]); a1 += bf2f(h[1]); a2 += bf2f(h[2]); a3 += bf2f(h[3]);
  }
  float4 r; r.x = a0; r.y = a1; r.z = a2; r.w = a3;
  ((float4*)out)[i] = r;
}

// ---------------- GEMM C = A * B^T, A[M,ldk] bf16, B[N,ldk] bf16 ----------------
// BM=BN=128, BK=64; 4 waves in 2x2, wave tile 64x64 (acc 4x4 in AGPR).
// DOUBLE-BUFFERED with COUNTED vmcnt (T4): per iter
//   wait vmcnt(8) [tile i landed, tile i+1's 8 loads stay IN FLIGHT]
//   -> s_barrier -> compute buf[cur] -> s_barrier -> issue tile i+2 into buf[cur].
// No __syncthreads in the loop (its implicit vmcnt(0) drains the prefetch --
// R10 measured that as a 9us regression). Barriers are the CONVERGENT builtin
// __builtin_amdgcn_s_barrier (R11's raw-asm barriers are the one construct the
// compiler may legally mangle; builtin is the m201-verified form). vmcnt ledger
// verified for niter=4,16; 8 loads/thread/tile so counts are exact.
// m201 st_16x32 swizzle via pre-swizzled global src (LDS dest wave-uniform
// linear, m104/m108). M fixed 4096 -> 32 m-blocks; grid id = mb+32*(nb+NB*kz).
template <class Epi>
__global__ __launch_bounds__(256, 2)
void gemm_bt(const u16* __restrict__ A, const u16* __restrict__ Bw,
             int ldk, int K, int NB, Epi epi) {
  __shared__ __align__(16) u16 As[2][128 * 64];   // 2 x 16 KB
  __shared__ __align__(16) u16 Bs[2][128 * 64];   // 2 x 16 KB
  const int tid = threadIdx.x;
  const int wave = tid >> 6, lane = tid & 63;
  const int quad = lane >> 4, l16 = lane & 15;
  const int wr = wave >> 1, wc = wave & 1;
  const int id = blockIdx.x;
  const int mb = id & 31;
  const int t = id >> 5;
  const int nb = t % NB;
  const int kz = t / NB;
  const int bm = mb * 128, bn = nb * 128;

  const int rowg = wave * 8 + (lane >> 3);    // 0..31 row within a 32-row slab
  const int chunk = lane & 7;                 // 16B chunk slot this lane fills
  const int scol = (chunk ^ (2 * ((rowg >> 2) & 1))) * 8;  // inverse-swizzled src
  const u16* pa[4];
  const u16* pb[4];
#pragma unroll
  for (int j = 0; j < 4; j++) {               // slab j covers rows j*32..j*32+31
    pa[j] = A + (size_t)(bm + j * 32 + rowg) * ldk + (size_t)kz * K + scol;
    pb[j] = Bw + (size_t)(bn + j * 32 + rowg) * ldk + (size_t)kz * K + scol;
  }
  const int ldst = wave * 512;                // wave-uniform dest offset in slab

  const f32x4 fz = {0.f, 0.f, 0.f, 0.f};
  f32x4 acc[4][4];
#pragma unroll
  for (int i = 0; i < 4; i++)
#pragma unroll
    for (int j = 0; j < 4; j++) acc[i][j] = fz;

  const int qsw = (quad ^ (2 * ((l16 >> 2) & 1))) * 8;  // swizzled 16B slot

  // prologue: tiles 0 and 1 (16 loads/thread outstanding)
#pragma unroll
  for (int j = 0; j < 4; j++) { async_load16(pa[j], &As[0][j * 2048 + ldst]); pa[j] += 64; }
#pragma unroll
  for (int j = 0; j < 4; j++) { async_load16(pb[j], &Bs[0][j * 2048 + ldst]); pb[j] += 64; }
#pragma unroll
  for (int j = 0; j < 4; j++) { async_load16(pa[j], &As[1][j * 2048 + ldst]); pa[j] += 64; }
#pragma unroll
  for (int j = 0; j < 4; j++) { async_load16(pb[j], &Bs[1][j * 2048 + ldst]); pb[j] += 64; }

  const int niter = K >> 6;
  for (int i = 0; i < niter; i++) {
    const int cur = i & 1;
    // tile i complete; tile i+1's 8 loads (if any) remain in flight
    if (i + 1 < niter) { asm volatile("s_waitcnt vmcnt(8)" ::: "memory"); }
    else               { asm volatile("s_waitcnt vmcnt(0)" ::: "memory"); }
    __builtin_amdgcn_s_barrier();
#pragma unroll
    for (int kk = 0; kk < 2; kk++) {
      const int slot = qsw + kk * 32;
      bf16x8 af[4], bfr[4];
#pragma unroll
      for (int mi = 0; mi < 4; mi++)
        af[mi] = *(const bf16x8*)&As[cur][(wr * 64 + mi * 16 + l16) * 64 + slot];
#pragma unroll
      for (int ni = 0; ni < 4; ni++)
        bfr[ni] = *(const bf16x8*)&Bs[cur][(wc * 64 + ni * 16 + l16) * 64 + slot];
#pragma unroll
      for (int mi = 0; mi < 4; mi++)
#pragma unroll
        for (int ni = 0; ni < 4; ni++)
          acc[mi][ni] = __builtin_amdgcn_mfma_f32_16x16x32_bf16(af[mi], bfr[ni], acc[mi][ni], 0, 0, 0);
    }
    __builtin_amdgcn_s_barrier();             // all waves done reading buf[cur]
    if (i + 2 < niter) {                      // refill buf[cur] with tile i+2
#pragma unroll
      for (int j = 0; j < 4; j++) { async_load16(pa[j], &As[cur][j * 2048 + ldst]); pa[j] += 64; }
#pragma unroll
      for (int j = 0; j < 4; j++) { async_load16(pb[j], &Bs[cur][j * 2048 + ldst]); pb[j] += 64; }
    }
  }
#pragma unroll
  for (int mi = 0; mi < 4; mi++)
#pragma unroll
    for (int ni = 0; ni < 4; ni++)
      epi(bm + wr * 64 + mi * 16 + quad * 4, bn + wc * 64 + ni * 16 + l16, kz, acc[mi][ni]);
}

// ---------------- epilogues (rows m0..m0+3, col n) ----------------
struct EpiQKV {   // q[b,h,s,e] scaled by 0.125*log2(e); k[b,h,s,e]; v^T[b,h,e,s]
  u16 *q, *k, *vt; const float *bq, *bk, *bv;
  __device__ void operator()(int m0, int n, int, f32x4 v) const {
    const int which = n >> 10, nn = n & 1023;
    const int hh = nn >> 6, e = nn & 63;
    const int bb = m0 >> 11, s0 = m0 & 2047;
    const size_t bh = (size_t)(bb * 16 + hh);
    if (which == 0) {
      const float bias = bq[nn];
      u16* p = &q[(bh * 2048 + s0) * 64 + e];
#pragma unroll
      for (int r = 0; r < 4; r++) p[r * 64] = bf_bits((v[r] + bias) * 0.18033688f);
    } else if (which == 1) {
      const float bias = bk[nn];
      u16* p = &k[(bh * 2048 + s0) * 64 + e];
#pragma unroll
      for (int r = 0; r < 4; r++) p[r * 64] = bf_bits(v[r] + bias);
    } else {
      const float bias = bv[nn];
      bf16x4 pk;
#pragma unroll
      for (int r = 0; r < 4; r++) pk[r] = (__bf16)(v[r] + bias);
      *(bf16x4*)&vt[(bh * 64 + e) * 2048 + s0] = pk;
    }
  }
};
struct EpiPartB {  // bf16 split-K partial -> p + kz*4194304  ([4096,1024] bf16)
  u16* p;
  __device__ void operator()(int m0, int n, int kz, f32x4 v) const {
    u16* pp = p + (size_t)kz * 4194304;
#pragma unroll
    for (int r = 0; r < 4; r++) pp[(size_t)(m0 + r) * 1024 + n] = bf_bits(v[r]);
  }
};
struct EpiGelu {  // gelu(u) = u * sigmoid(2*c*(u+0.044715u^3)) via exp2
  const float* b1; u16* o;
  __device__ void operator()(int m0, int n, int, f32x4 v) const {
    const float bias = b1[n];
#pragma unroll
    for (int r = 0; r < 4; r++) {
      const float u = v[r] + bias;
      const float z2 = u * (2.3021183f + 0.10294515f * u * u);
      const float d = 1.0f + exp2_fast(-z2);
      o[(size_t)(m0 + r) * 4096 + n] = bf_bits(u * rcp_fast(d));
    }
  }
};

// ---------------- flash attention, no-max softmax, KVBLK=128, 1 wave = 32 q-rows ----
// K LDS rows permuted (row u holds K[kv = 8*(u&15)+(u>>4)]) so the P tile lands
// in true-kv order as contiguous bf16x8 stores; V^T staged unpermuted.
__global__ __launch_bounds__(256)
void attn_kernel(const u16* __restrict__ Q, const u16* __restrict__ K,
                 const u16* __restrict__ Vt, u16* __restrict__ O) {
  __shared__ __align__(16) u16 Ks[128 * 72];    // 18.4 KB (K rows, 64 d + pad)
  __shared__ __align__(16) u16 Vs[64 * 136];    // 17.4 KB (e rows, 128 s + pad)
  __shared__ __align__(16) u16 Ps[4][32 * 136]; // 34.8 KB (per-wave P tiles)
  const int tid = threadIdx.x, wave = tid >> 6, lane = tid & 63;
  const int quad = lane >> 4, l16 = lane & 15;
  const int b = blockIdx.z, h = blockIdx.y, qt = blockIdx.x;
  const size_t bh = (size_t)(b * 16 + h);
  const u16* Qp = Q + bh * (size_t)(2048 * 64);
  const u16* Kp = K + bh * (size_t)(2048 * 64);
  const u16* Vp = Vt + bh * (size_t)(64 * 2048);
  const int q0 = qt * 128 + wave * 32;

  bf16x8 qf[2][2];
#pragma unroll
  for (int rg = 0; rg < 2; rg++) {
    const u16* qrow = &Qp[(size_t)(q0 + rg * 16 + l16) * 64 + quad * 8];
    qf[rg][0] = *(const bf16x8*)qrow;
    qf[rg][1] = *(const bf16x8*)(qrow + 32);
  }

  // K staging: 128 rows x 64 d / 256 thr = 32 u16/thr (half a row)
  const int srK = tid >> 1, scK = (tid & 1) * 32;
  const int krow = 8 * (srK & 15) + (srK >> 4);        // permuted key row
  const u16* kg = &Kp[(size_t)krow * 64 + scK];
  u16* kl = &Ks[srK * 72 + scK];
  // V staging: 64 e-rows x 128 s / 256 thr = 32 u16/thr
  const int srV = tid >> 2, scV = (tid & 3) * 32;
  const u16* vg = &Vp[(size_t)srV * 2048 + scV];
  u16* vl = &Vs[srV * 136 + scV];
  u16* Pw = &Ps[wave][0];

  bf16x8 ones;
#pragma unroll
  for (int i = 0; i < 8; i++) ones[i] = (__bf16)1.0f;

  const f32x4 fz = {0.f, 0.f, 0.f, 0.f};
  f32x4 acc[2][4], lsum[2];
#pragma unroll
  for (int rg = 0; rg < 2; rg++) {
    lsum[rg] = fz;
#pragma unroll
    for (int g = 0; g < 4; g++) acc[rg][g] = fz;
  }

  bf16x8 pk[4], pv[4];
#pragma unroll
  for (int c = 0; c < 4; c++) {
    pk[c] = *(const bf16x8*)(kg + 8 * c);
    pv[c] = *(const bf16x8*)(vg + 8 * c);
  }

  for (int t0 = 0; t0 < 2048; t0 += 128) {
#pragma unroll
    for (int c = 0; c < 4; c++) {
      *(bf16x8*)(kl + 8 * c) = pk[c];
      *(bf16x8*)(vl + 8 * c) = pv[c];
    }
    __syncthreads();
    kg += 128 * 64; vg += 128;
#pragma unroll
    for (int c = 0; c < 4; c++) {        // over-reads 1 tile past end: lands in
      pk[c] = *(const bf16x8*)(kg + 8 * c);   // the next ws buffer, unused
      pv[c] = *(const bf16x8*)(vg + 8 * c);
    }

    // ---- QK^T, first half (kv tiles g 0..3) ----
    f32x4 s[2][4];
    __builtin_amdgcn_s_setprio(1);
#pragma unroll
    for (int g = 0; g < 4; g++) {
      const u16* kr = &Ks[(g * 16 + l16) * 72 + quad * 8];
      const bf16x8 kb0 = *(const bf16x8*)kr;
      const bf16x8 kb1 = *(const bf16x8*)(kr + 32);
#pragma unroll
      for (int rg = 0; rg < 2; rg++) {
        f32x4 z = __builtin_amdgcn_mfma_f32_16x16x32_bf16(qf[rg][0], kb0, fz, 0, 0, 0);
        s[rg][g] = __builtin_amdgcn_mfma_f32_16x16x32_bf16(qf[rg][1], kb1, z, 0, 0, 0);
      }
    }
    __builtin_amdgcn_s_setprio(0);
#pragma unroll
    for (int rg = 0; rg < 2; rg++)
#pragma unroll
      for (int r = 0; r < 4; r++) {
        f32x4 pf;
#pragma unroll
        for (int g = 0; g < 4; g++) pf[g] = exp2_fast(s[rg][g][r]);
        const bf16x4 pb = __builtin_convertvector(pf, bf16x4);
        *(bf16x4*)&Pw[(rg * 16 + quad * 4 + r) * 136 + 8 * l16] = pb;
      }
    // ---- QK^T, second half (kv tiles g 4..7) ----
    __builtin_amdgcn_s_setprio(1);
#pragma unroll
    for (int g = 0; g < 4; g++) {
      const u16* kr = &Ks[((g + 4) * 16 + l16) * 72 + quad * 8];
      const bf16x8 kb0 = *(const bf16x8*)kr;
      const bf16x8 kb1 = *(const bf16x8*)(kr + 32);
#pragma unroll
      for (int rg = 0; rg < 2; rg++) {
        f32x4 z = __builtin_amdgcn_mfma_f32_16x16x32_bf16(qf[rg][0], kb0, fz, 0, 0, 0);
        s[rg][g] = __builtin_amdgcn_mfma_f32_16x16x32_bf16(qf[rg][1], kb1, z, 0, 0, 0);
      }
    }
    __builtin_amdgcn_s_setprio(0);
#pragma unroll
    for (int rg = 0; rg < 2; rg++)
#pragma unroll
      for (int r = 0; r < 4; r++) {
        f32x4 pf;
#pragma unroll
        for (int g = 0; g < 4; g++) pf[g] = exp2_fast(s[rg][g][r]);
        const bf16x4 pb = __builtin_convertvector(pf, bf16x4);
        *(bf16x4*)&Pw[(rg * 16 + quad * 4 + r) * 136 + 8 * l16 + 4] = pb;
      }

    // ---- P readback (true kv order) + row-sum + PV ----
    bf16x8 pa[2][4];
#pragma unroll
    for (int rg = 0; rg < 2; rg++)
#pragma unroll
      for (int hh2 = 0; hh2 < 4; hh2++) {
        pa[rg][hh2] = *(const bf16x8*)&Pw[(rg * 16 + l16) * 136 + quad * 8 + hh2 * 32];
        lsum[rg] = __builtin_amdgcn_mfma_f32_16x16x32_bf16(pa[rg][hh2], ones, lsum[rg], 0, 0, 0);
      }
    __builtin_amdgcn_s_setprio(1);
#pragma unroll
    for (int g = 0; g < 4; g++) {
      const u16* vr = &Vs[(g * 16 + l16) * 136 + quad * 8];
#pragma unroll
      for (int hh2 = 0; hh2 < 4; hh2++) {
        const bf16x8 vb = *(const bf16x8*)(vr + hh2 * 32);
#pragma unroll
        for (int rg = 0; rg < 2; rg++)
          acc[rg][g] = __builtin_amdgcn_mfma_f32_16x16x32_bf16(pa[rg][hh2], vb, acc[rg][g], 0, 0, 0);
      }
    }
    __builtin_amdgcn_s_setprio(0);
    __syncthreads();
  }
#pragma unroll
  for (int rg = 0; rg < 2; rg++)
#pragma unroll
    for (int r = 0; r < 4; r++) {
      const float inv = rcp_fast(lsum[rg][r]);
      const int s_row = q0 + rg * 16 + quad * 4 + r;
      u16* op = (u16*)&O[((size_t)(b * 2048 + s_row)) * 1024 + h * 64 + l16];
#pragma unroll
      for (int g = 0; g < 4; g++) op[g * 16] = bf_bits(acc[rg][g][r] * inv);
    }
}

// ---------------- launch ----------------
extern "C" void kernel_launch(void* const* d_in, const int* in_sizes, int n_in,
                              void* d_out, int out_size, void* d_ws, size_t ws_size,
                              hipStream_t stream) {
  const float* x   = (const float*)d_in[0];
  const float* Wq  = (const float*)d_in[1];
  const float* bq  = (const float*)d_in[2];
  const float* Wk  = (const float*)d_in[3];
  const float* bk  = (const float*)d_in[4];
  const float* Wv  = (const float*)d_in[5];
  const float* bv  = (const float*)d_in[6];
  const float* Wo  = (const float*)d_in[7];
  const float* bo  = (const float*)d_in[8];
  const float* g1  = (const float*)d_in[9];
  const float* be1 = (const float*)d_in[10];
  const float* W1  = (const float*)d_in[11];
  const float* b1  = (const float*)d_in[12];
  const float* W2  = (const float*)d_in[13];
  const float* b2  = (const float*)d_in[14];
  const float* g2  = (const float*)d_in[15];
  const float* be2 = (const float*)d_in[16];
  float* out = (float*)d_out;

  char* w = (char*)d_ws;
  u16* wqkv = (u16*)w; w += (size_t)3072 * 1024 * 2;   // contiguous bf16 weights:
  u16* wob  = (u16*)w; w += (size_t)1024 * 1024 * 2;   //   wqkv|wob|w1b|w2b
  u16* w1b  = (u16*)w; w += (size_t)4096 * 1024 * 2;
  u16* w2b  = (u16*)w; w += (size_t)1024 * 4096 * 2;
  u16* hb   = (u16*)w; w += (size_t)4096 * 1024 * 2;
  u16* qb   = (u16*)w; w += (size_t)4096 * 1024 * 2;   // later: MLP2 partials (4x8MB
  u16* kb   = (u16*)w; w += (size_t)4096 * 1024 * 2;   //   bf16 spanning qb..atb)
  u16* vtb  = (u16*)w; w += (size_t)4096 * 1024 * 2;
  u16* atb  = (u16*)w; w += (size_t)4096 * 1024 * 2;
  u16* m1b  = (u16*)w; w += (size_t)4096 * 4096 * 2;   // O-proj partials first (2x8MB)

  u16* op_part = m1b;   // O-proj bf16 partials, dead before MLP1 writes m1b
  u16* ml_part = qb;    // MLP2 bf16 partials, qb..atb all dead after O-proj

  f2b_all<<<12288, 256, 0, stream>>>(Wq, Wk, Wv, Wo, W1, W2, wqkv);

  ln_kernel<<<4096, 256, 0, stream>>>(x, g1, be1, hb);
  // QKV: M=4096, N=3072, K=1024 -> grid 32*24 = 768
  gemm_bt<EpiQKV><<<768, 256, 0, stream>>>(hb, wqkv, 1024, 1024, 24,
      EpiQKV{qb, kb, vtb, bq, bk, bv});
  attn_kernel<<<dim3(16, 16, 2), 256, 0, stream>>>(qb, kb, vtb, atb);
  // O-proj: N=1024, K=1024 split 2 -> grid 32*8*2 = 512
  gemm_bt<EpiPartB><<<512, 256, 0, stream>>>(atb, wob, 1024, 512, 8,
      EpiPartB{op_part});
  ln_fuse<<<4096, 256, 0, stream>>>(x, op_part, bo, g2, be2, out, hb);
  // MLP1: N=4096, K=1024 -> grid 32*32 = 1024
  gemm_bt<EpiGelu><<<1024, 256, 0, stream>>>(hb, w1b, 1024, 1024, 32,
      EpiGelu{b1, m1b});
  // MLP2: N=1024, K=4096 split 4 -> grid 32*8*4 = 1024
  gemm_bt<EpiPartB><<<1024, 256, 0, stream>>>(m1b, w2b, 4096, 1024, 8,
      EpiPartB{ml_part});
  add4<<<4096, 256, 0, stream>>>(out, ml_part, b2);
}

// Round 13
// 339.694 us; speedup vs baseline: 1.0263x; 1.0049x over previous
//
#include <hip/hip_runtime.h>

typedef unsigned short u16;
typedef __attribute__((ext_vector_type(8))) __bf16 bf16x8;
typedef __attribute__((ext_vector_type(4))) __bf16 bf16x4;
typedef __attribute__((ext_vector_type(4))) float f32x4;
typedef __attribute__((ext_vector_type(4))) unsigned short u16x4;

#define AS1 __attribute__((address_space(1)))
#define AS3 __attribute__((address_space(3)))

__device__ __forceinline__ void async_load16(const void* g, void* l) {
  __builtin_amdgcn_global_load_lds((const AS1 void*)g, (AS3 void*)l, 16, 0, 0);
}

__device__ __forceinline__ float exp2_fast(float x) {
#if __has_builtin(__builtin_amdgcn_exp2f)
  return __builtin_amdgcn_exp2f(x);
#else
  return exp2f(x);
#endif
}
__device__ __forceinline__ float rcp_fast(float x) {
#if __has_builtin(__builtin_amdgcn_rcpf)
  return __builtin_amdgcn_rcpf(x);
#else
  return 1.0f / x;
#endif
}

__device__ __forceinline__ u16 f2bf(float f) {   // manual RNE
  union { float f; unsigned u; } a; a.f = f;
  unsigned u = a.u;
  u += 0x7fffu + ((u >> 16) & 1u);
  return (u16)(u >> 16);
}
__device__ __forceinline__ u16 bf_bits(float f) {  // native cvt (RNE)
  union { __bf16 b; u16 u; } c; c.b = (__bf16)f; return c.u;
}
__device__ __forceinline__ float bf2f(u16 h) {
  union { unsigned u; float f; } c; c.u = ((unsigned)h) << 16; return c.f;
}

// ------- fp32 -> bf16: all 6 weights in ONE launch (dst contiguous in ws) -------
__global__ __launch_bounds__(256)
void f2b_all(const float* __restrict__ s0, const float* __restrict__ s1,
             const float* __restrict__ s2, const float* __restrict__ s3,
             const float* __restrict__ s4, const float* __restrict__ s5,
             u16* __restrict__ dst) {
  const int i = blockIdx.x * 256 + threadIdx.x;   // < 3145728
  const float* s; int off;
  if (i < 1048576) {
    if (i < 262144)      { s = s0; off = i; }
    else if (i < 524288) { s = s1; off = i - 262144; }
    else if (i < 786432) { s = s2; off = i - 524288; }
    else                 { s = s3; off = i - 786432; }
  } else if (i < 2097152) { s = s4; off = i - 1048576; }
  else                    { s = s5; off = i - 2097152; }
  const float4 v = ((const float4*)s)[off];
  u16x4 o; o[0] = f2bf(v.x); o[1] = f2bf(v.y); o[2] = f2bf(v.z); o[3] = f2bf(v.w);
  ((u16x4*)dst)[i] = o;
}

// ---------------- LayerNorm (1024 cols, 1 block/row) ----------------
__global__ __launch_bounds__(256)
void ln_kernel(const float* __restrict__ x, const float* __restrict__ g,
               const float* __restrict__ b, u16* __restrict__ out) {
  const int row = blockIdx.x, tid = threadIdx.x;
  const float4 v = ((const float4*)(x + (size_t)row * 1024))[tid];
  float s = v.x + v.y + v.z + v.w;
  float s2 = v.x * v.x + v.y * v.y + v.z * v.z + v.w * v.w;
#pragma unroll
  for (int o = 1; o < 64; o <<= 1) { s += __shfl_xor(s, o); s2 += __shfl_xor(s2, o); }
  __shared__ float red[8];
  const int wave = tid >> 6, lane = tid & 63;
  if (lane == 0) { red[wave] = s; red[wave + 4] = s2; }
  __syncthreads();
  s = red[0] + red[1] + red[2] + red[3];
  s2 = red[4] + red[5] + red[6] + red[7];
  const float mu = s * (1.f / 1024.f);
  const float rstd = rsqrtf(s2 * (1.f / 1024.f) - mu * mu + 1e-5f);
  const float4 gg = ((const float4*)g)[tid];
  const float4 bb = ((const float4*)b)[tid];
  u16x4 o4;
  o4[0] = f2bf((v.x - mu) * rstd * gg.x + bb.x);
  o4[1] = f2bf((v.y - mu) * rstd * gg.y + bb.y);
  o4[2] = f2bf((v.z - mu) * rstd * gg.z + bb.z);
  o4[3] = f2bf((v.w - mu) * rstd * gg.w + bb.w);
  ((u16x4*)(out + (size_t)row * 1024))[tid] = o4;
}

// -- fused: out = x + p[0] + p[1] + bo (bf16 partials); hb = LN(out; g,b) --
__global__ __launch_bounds__(256)
void ln_fuse(const float* __restrict__ x, const u16* __restrict__ parts,
             const float* __restrict__ bo, const float* __restrict__ g,
             const float* __restrict__ b, float* __restrict__ out,
             u16* __restrict__ hb) {
  const int row = blockIdx.x, tid = threadIdx.x;
  const size_t base = (size_t)row * 1024;
  const int i4 = row * 256 + tid;
  const float4 xv = ((const float4*)(x + base))[tid];
  const u16x4 h0 = ((const u16x4*)parts)[i4];
  const u16x4 h1 = ((const u16x4*)(parts + 4194304))[i4];
  const float4 bv = ((const float4*)bo)[tid];
  float4 t;
  t.x = xv.x + bf2f(h0[0]) + bf2f(h1[0]) + bv.x;
  t.y = xv.y + bf2f(h0[1]) + bf2f(h1[1]) + bv.y;
  t.z = xv.z + bf2f(h0[2]) + bf2f(h1[2]) + bv.z;
  t.w = xv.w + bf2f(h0[3]) + bf2f(h1[3]) + bv.w;
  ((float4*)(out + base))[tid] = t;
  float s = t.x + t.y + t.z + t.w;
  float s2 = t.x * t.x + t.y * t.y + t.z * t.z + t.w * t.w;
#pragma unroll
  for (int o = 1; o < 64; o <<= 1) { s += __shfl_xor(s, o); s2 += __shfl_xor(s2, o); }
  __shared__ float red[8];
  const int wave = tid >> 6, lane = tid & 63;
  if (lane == 0) { red[wave] = s; red[wave + 4] = s2; }
  __syncthreads();
  s = red[0] + red[1] + red[2] + red[3];
  s2 = red[4] + red[5] + red[6] + red[7];
  const float mu = s * (1.f / 1024.f);
  const float rstd = rsqrtf(s2 * (1.f / 1024.f) - mu * mu + 1e-5f);
  const float4 gg = ((const float4*)g)[tid];
  const float4 bb = ((const float4*)b)[tid];
  u16x4 o4;
  o4[0] = f2bf((t.x - mu) * rstd * gg.x + bb.x);
  o4[1] = f2bf((t.y - mu) * rstd * gg.y + bb.y);
  o4[2] = f2bf((t.z - mu) * rstd * gg.z + bb.z);
  o4[3] = f2bf((t.w - mu) * rstd * gg.w + bb.w);
  ((u16x4*)(hb + base))[tid] = o4;
}

// ------- out += p[0..3] + b2 (MLP2 reduction over 4 bf16 partial slices) -------
__global__ __launch_bounds__(256)
void add4(float* __restrict__ out, const u16* __restrict__ p,
          const float* __restrict__ b2) {
  const int i = blockIdx.x * 256 + threadIdx.x;   // f4 index < 1048576
  const float4 o = ((const float4*)out)[i];
  const float4 bv = ((const float4*)b2)[i & 255];
  float a0 = o.x + bv.x, a1 = o.y + bv.y, a2 = o.z + bv.z, a3 = o.w + bv.w;
#pragma unroll
  for (int kz = 0; kz < 4; kz++) {
    const u16x4 h = ((const u16x4*)(p + (size_t)kz * 4194304))[i];
    a0 += bf2f(h[0]); a1 += bf2f(h[1]); a2 += bf2f(h[2]); a3 += bf2f(h[3]);
  }
  float4 r; r.x = a0; r.y = a1; r.z = a2; r.w = a3;
  ((float4*)out)[i] = r;
}

// ---------------- GEMM C = A * B^T, A[M,ldk] bf16, B[N,ldk] bf16 ----------------
// R6-proven form: BM=256, BN=128, BK=64; 4 waves, wave tile 64x128 (acc 4x8).
// 2-barrier structure; m201-exact st_16x32 swizzle (chunk-bit1 ^= row-bit2)
// staged via pre-swizzled global src (dest wave-uniform linear, m104/m108).
template <class Epi>
__global__ __launch_bounds__(256, 2)
void gemm_bt(const u16* __restrict__ A, const u16* __restrict__ Bw,
             int ldk, int K, int NB, Epi epi) {
  __shared__ __align__(16) u16 As[256 * 64];   // 32 KB
  __shared__ __align__(16) u16 Bs[128 * 64];   // 16 KB
  const int tid = threadIdx.x;
  const int wave = tid >> 6, lane = tid & 63;
  const int quad = lane >> 4, l16 = lane & 15;
  const int id = blockIdx.x;
  const int mb = id & 15;
  const int t = id >> 4;
  const int nb = t % NB;
  const int kz = t / NB;
  const int bm = mb * 256, bn = nb * 128;
  const int wm = wave * 64;

  const int srow = lane >> 3;                 // 0..7 (row within 8-row block)
  const int chunk = lane & 7;                 // 16B chunk slot this lane fills
  const int scol = (chunk ^ (2 * ((srow >> 2) & 1))) * 8;  // inverse-swizzled src
  const u16* pa[8];
  u16* la[8];
#pragma unroll
  for (int j = 0; j < 8; j++) {
    pa[j] = A + (size_t)(bm + wave * 64 + j * 8 + srow) * ldk + (size_t)kz * K + scol;
    la[j] = &As[wave * 4096 + j * 512];       // wave-uniform dest
  }
  const u16* pb[4];
  u16* lb[4];
#pragma unroll
  for (int j = 0; j < 4; j++) {
    pb[j] = Bw + (size_t)(bn + wave * 32 + j * 8 + srow) * ldk + (size_t)kz * K + scol;
    lb[j] = &Bs[wave * 2048 + j * 512];
  }

  const f32x4 fz = {0.f, 0.f, 0.f, 0.f};
  f32x4 acc[4][8];
#pragma unroll
  for (int i = 0; i < 4; i++)
#pragma unroll
    for (int j = 0; j < 8; j++) acc[i][j] = fz;

  const int qsw = (quad ^ (2 * ((l16 >> 2) & 1))) * 8;  // swizzled 16B slot

  for (int k0 = 0; k0 < K; k0 += 64) {
#pragma unroll
    for (int j = 0; j < 8; j++) { async_load16(pa[j], la[j]); pa[j] += 64; }
#pragma unroll
    for (int j = 0; j < 4; j++) { async_load16(pb[j], lb[j]); pb[j] += 64; }
    __syncthreads();
#pragma unroll
    for (int kk = 0; kk < 2; kk++) {
      const int slot = qsw + kk * 32;
      bf16x8 af[4], bfr[8];
#pragma unroll
      for (int mi = 0; mi < 4; mi++)
        af[mi] = *(const bf16x8*)&As[(wm + mi * 16 + l16) * 64 + slot];
#pragma unroll
      for (int ni = 0; ni < 8; ni++)
        bfr[ni] = *(const bf16x8*)&Bs[(ni * 16 + l16) * 64 + slot];
#pragma unroll
      for (int mi = 0; mi < 4; mi++)
#pragma unroll
        for (int ni = 0; ni < 8; ni++)
          acc[mi][ni] = __builtin_amdgcn_mfma_f32_16x16x32_bf16(af[mi], bfr[ni], acc[mi][ni], 0, 0, 0);
    }
    __syncthreads();
  }
#pragma unroll
  for (int mi = 0; mi < 4; mi++)
#pragma unroll
    for (int ni = 0; ni < 8; ni++)
      epi(bm + wm + mi * 16 + quad * 4, bn + ni * 16 + l16, kz, acc[mi][ni]);
}

// ---------------- epilogues (rows m0..m0+3, col n) ----------------
struct EpiQKV {   // q[b,h,s,e] scaled by 0.125*log2(e); k[b,h,s,e]; v^T[b,h,e,s]
  u16 *q, *k, *vt; const float *bq, *bk, *bv;
  __device__ void operator()(int m0, int n, int, f32x4 v) const {
    const int which = n >> 10, nn = n & 1023;
    const int hh = nn >> 6, e = nn & 63;
    const int bb = m0 >> 11, s0 = m0 & 2047;
    const size_t bh = (size_t)(bb * 16 + hh);
    if (which == 0) {
      const float bias = bq[nn];
      u16* p = &q[(bh * 2048 + s0) * 64 + e];
#pragma unroll
      for (int r = 0; r < 4; r++) p[r * 64] = bf_bits((v[r] + bias) * 0.18033688f);
    } else if (which == 1) {
      const float bias = bk[nn];
      u16* p = &k[(bh * 2048 + s0) * 64 + e];
#pragma unroll
      for (int r = 0; r < 4; r++) p[r * 64] = bf_bits(v[r] + bias);
    } else {
      const float bias = bv[nn];
      bf16x4 pk;
#pragma unroll
      for (int r = 0; r < 4; r++) pk[r] = (__bf16)(v[r] + bias);
      *(bf16x4*)&vt[(bh * 64 + e) * 2048 + s0] = pk;
    }
  }
};
struct EpiPartB {  // bf16 split-K partial -> p + kz*4194304  ([4096,1024] bf16)
  u16* p;
  __device__ void operator()(int m0, int n, int kz, f32x4 v) const {
    u16* pp = p + (size_t)kz * 4194304;
#pragma unroll
    for (int r = 0; r < 4; r++) pp[(size_t)(m0 + r) * 1024 + n] = bf_bits(v[r]);
  }
};
struct EpiGelu {  // gelu(u) = u * sigmoid(2*c*(u+0.044715u^3)) via exp2
  const float* b1; u16* o;
  __device__ void operator()(int m0, int n, int, f32x4 v) const {
    const float bias = b1[n];
#pragma unroll
    for (int r = 0; r < 4; r++) {
      const float u = v[r] + bias;
      const float z2 = u * (2.3021183f + 0.10294515f * u * u);
      const float d = 1.0f + exp2_fast(-z2);
      o[(size_t)(m0 + r) * 4096 + n] = bf_bits(u * rcp_fast(d));
    }
  }
};

// ---------------- flash attention, no-max softmax, KVBLK=128, 1 wave = 32 q-rows ----
// K LDS rows permuted PER 64-GROUP (row u in group g64 holds K[kv = g64*64 +
// 4*(u&15)+(u>>4)]) so each QK^T HALF yields a contiguous true-order P half
// (cols 0..63 / 64..127). Phase order exposes trans/MFMA overlap: QK1 -> pack1
// -> QK2 (indep of pack1) -> readback1+lsum+PV1 -> pack2 (indep of PV1) ->
// readback2+lsum+PV2. V^T staged unpermuted.
__global__ __launch_bounds__(256)
void attn_kernel(const u16* __restrict__ Q, const u16* __restrict__ K,
                 const u16* __restrict__ Vt, u16* __restrict__ O) {
  __shared__ __align__(16) u16 Ks[128 * 72];    // 18.4 KB (K rows, 64 d + pad)
  __shared__ __align__(16) u16 Vs[64 * 136];    // 17.4 KB (e rows, 128 s + pad)
  __shared__ __align__(16) u16 Ps[4][32 * 136]; // 34.8 KB (per-wave P tiles)
  const int tid = threadIdx.x, wave = tid >> 6, lane = tid & 63;
  const int quad = lane >> 4, l16 = lane & 15;
  const int b = blockIdx.z, h = blockIdx.y, qt = blockIdx.x;
  const size_t bh = (size_t)(b * 16 + h);
  const u16* Qp = Q + bh * (size_t)(2048 * 64);
  const u16* Kp = K + bh * (size_t)(2048 * 64);
  const u16* Vp = Vt + bh * (size_t)(64 * 2048);
  const int q0 = qt * 128 + wave * 32;

  bf16x8 qf[2][2];
#pragma unroll
  for (int rg = 0; rg < 2; rg++) {
    const u16* qrow = &Qp[(size_t)(q0 + rg * 16 + l16) * 64 + quad * 8];
    qf[rg][0] = *(const bf16x8*)qrow;
    qf[rg][1] = *(const bf16x8*)(qrow + 32);
  }

  // K staging: 128 rows x 64 d / 256 thr = 32 u16/thr (half a row)
  const int srK = tid >> 1, scK = (tid & 1) * 32;
  const int uK = srK & 63, gK = srK >> 6;
  const int krow = gK * 64 + 4 * (uK & 15) + (uK >> 4);   // per-group permuted
  const u16* kg = &Kp[(size_t)krow * 64 + scK];
  u16* kl = &Ks[srK * 72 + scK];
  // V staging: 64 e-rows x 128 s / 256 thr = 32 u16/thr
  const int srV = tid >> 2, scV = (tid & 3) * 32;
  const u16* vg = &Vp[(size_t)srV * 2048 + scV];
  u16* vl = &Vs[srV * 136 + scV];
  u16* Pw = &Ps[wave][0];

  bf16x8 ones;
#pragma unroll
  for (int i = 0; i < 8; i++) ones[i] = (__bf16)1.0f;

  const f32x4 fz = {0.f, 0.f, 0.f, 0.f};
  f32x4 acc[2][4], lsum[2];
#pragma unroll
  for (int rg = 0; rg < 2; rg++) {
    lsum[rg] = fz;
#pragma unroll
    for (int g = 0; g < 4; g++) acc[rg][g] = fz;
  }

  bf16x8 pk[4], pv[4];
#pragma unroll
  for (int c = 0; c < 4; c++) {
    pk[c] = *(const bf16x8*)(kg + 8 * c);
    pv[c] = *(const bf16x8*)(vg + 8 * c);
  }

  for (int t0 = 0; t0 < 2048; t0 += 128) {
#pragma unroll
    for (int c = 0; c < 4; c++) {
      *(bf16x8*)(kl + 8 * c) = pk[c];
      *(bf16x8*)(vl + 8 * c) = pv[c];
    }
    __syncthreads();
    kg += 128 * 64; vg += 128;
#pragma unroll
    for (int c = 0; c < 4; c++) {        // over-reads 1 tile past end: lands in
      pk[c] = *(const bf16x8*)(kg + 8 * c);   // the next ws buffer, unused
      pv[c] = *(const bf16x8*)(vg + 8 * c);
    }

    // ---- QK^T half1 (kv 0..63: Ks rows 0..63) ----
    f32x4 s1[2][4], s2[2][4];
    __builtin_amdgcn_s_setprio(1);
#pragma unroll
    for (int g = 0; g < 4; g++) {
      const u16* kr = &Ks[(g * 16 + l16) * 72 + quad * 8];
      const bf16x8 kb0 = *(const bf16x8*)kr;
      const bf16x8 kb1 = *(const bf16x8*)(kr + 32);
#pragma unroll
      for (int rg = 0; rg < 2; rg++) {
        f32x4 z = __builtin_amdgcn_mfma_f32_16x16x32_bf16(qf[rg][0], kb0, fz, 0, 0, 0);
        s1[rg][g] = __builtin_amdgcn_mfma_f32_16x16x32_bf16(qf[rg][1], kb1, z, 0, 0, 0);
      }
    }
    __builtin_amdgcn_s_setprio(0);
    // ---- pack1: P cols 0..63 (kv = 4*l16+g, true order) ----
#pragma unroll
    for (int rg = 0; rg < 2; rg++)
#pragma unroll
      for (int r = 0; r < 4; r++) {
        f32x4 pf;
#pragma unroll
        for (int g = 0; g < 4; g++) pf[g] = exp2_fast(s1[rg][g][r]);
        const bf16x4 pb = __builtin_convertvector(pf, bf16x4);
        *(bf16x4*)&Pw[(rg * 16 + quad * 4 + r) * 136 + 4 * l16] = pb;
      }
    // ---- QK^T half2 (kv 64..127) -- independent of pack1 ----
    __builtin_amdgcn_s_setprio(1);
#pragma unroll
    for (int g = 0; g < 4; g++) {
      const u16* kr = &Ks[((g + 4) * 16 + l16) * 72 + quad * 8];
      const bf16x8 kb0 = *(const bf16x8*)kr;
      const bf16x8 kb1 = *(const bf16x8*)(kr + 32);
#pragma unroll
      for (int rg = 0; rg < 2; rg++) {
        f32x4 z = __builtin_amdgcn_mfma_f32_16x16x32_bf16(qf[rg][0], kb0, fz, 0, 0, 0);
        s2[rg][g] = __builtin_amdgcn_mfma_f32_16x16x32_bf16(qf[rg][1], kb1, z, 0, 0, 0);
      }
    }
    __builtin_amdgcn_s_setprio(0);
    // ---- readback1 + lsum + PV half1 (s-cols 0..63) ----
    bf16x8 pa1[2][2];
#pragma unroll
    for (int rg = 0; rg < 2; rg++)
#pragma unroll
      for (int h2 = 0; h2 < 2; h2++) {
        pa1[rg][h2] = *(const bf16x8*)&Pw[(rg * 16 + l16) * 136 + quad * 8 + h2 * 32];
        lsum[rg] = __builtin_amdgcn_mfma_f32_16x16x32_bf16(pa1[rg][h2], ones, lsum[rg], 0, 0, 0);
      }
    __builtin_amdgcn_s_setprio(1);
#pragma unroll
    for (int g = 0; g < 4; g++) {
      const u16* vr = &Vs[(g * 16 + l16) * 136 + quad * 8];
#pragma unroll
      for (int h2 = 0; h2 < 2; h2++) {
        const bf16x8 vb = *(const bf16x8*)(vr + h2 * 32);
#pragma unroll
        for (int rg = 0; rg < 2; rg++)
          acc[rg][g] = __builtin_amdgcn_mfma_f32_16x16x32_bf16(pa1[rg][h2], vb, acc[rg][g], 0, 0, 0);
      }
    }
    __builtin_amdgcn_s_setprio(0);
    // ---- pack2: P cols 64..127 -- independent of PV half1 ----
#pragma unroll
    for (int rg = 0; rg < 2; rg++)
#pragma unroll
      for (int r = 0; r < 4; r++) {
        f32x4 pf;
#pragma unroll
        for (int g = 0; g < 4; g++) pf[g] = exp2_fast(s2[rg][g][r]);
        const bf16x4 pb = __builtin_convertvector(pf, bf16x4);
        *(bf16x4*)&Pw[(rg * 16 + quad * 4 + r) * 136 + 64 + 4 * l16] = pb;
      }
    // ---- readback2 + lsum + PV half2 (s-cols 64..127) ----
    bf16x8 pa2[2][2];
#pragma unroll
    for (int rg = 0; rg < 2; rg++)
#pragma unroll
      for (int h2 = 0; h2 < 2; h2++) {
        pa2[rg][h2] = *(const bf16x8*)&Pw[(rg * 16 + l16) * 136 + 64 + quad * 8 + h2 * 32];
        lsum[rg] = __builtin_amdgcn_mfma_f32_16x16x32_bf16(pa2[rg][h2], ones, lsum[rg], 0, 0, 0);
      }
    __builtin_amdgcn_s_setprio(1);
#pragma unroll
    for (int g = 0; g < 4; g++) {
      const u16* vr = &Vs[(g * 16 + l16) * 136 + quad * 8 + 64];
#pragma unroll
      for (int h2 = 0; h2 < 2; h2++) {
        const bf16x8 vb = *(const bf16x8*)(vr + h2 * 32);
#pragma unroll
        for (int rg = 0; rg < 2; rg++)
          acc[rg][g] = __builtin_amdgcn_mfma_f32_16x16x32_bf16(pa2[rg][h2], vb, acc[rg][g], 0, 0, 0);
      }
    }
    __builtin_amdgcn_s_setprio(0);
    __syncthreads();
  }
#pragma unroll
  for (int rg = 0; rg < 2; rg++)
#pragma unroll
    for (int r = 0; r < 4; r++) {
      const float inv = rcp_fast(lsum[rg][r]);
      const int s_row = q0 + rg * 16 + quad * 4 + r;
      u16* op = (u16*)&O[((size_t)(b * 2048 + s_row)) * 1024 + h * 64 + l16];
#pragma unroll
      for (int g = 0; g < 4; g++) op[g * 16] = bf_bits(acc[rg][g][r] * inv);
    }
}

// ---------------- launch ----------------
extern "C" void kernel_launch(void* const* d_in, const int* in_sizes, int n_in,
                              void* d_out, int out_size, void* d_ws, size_t ws_size,
                              hipStream_t stream) {
  const float* x   = (const float*)d_in[0];
  const float* Wq  = (const float*)d_in[1];
  const float* bq  = (const float*)d_in[2];
  const float* Wk  = (const float*)d_in[3];
  const float* bk  = (const float*)d_in[4];
  const float* Wv  = (const float*)d_in[5];
  const float* bv  = (const float*)d_in[6];
  const float* Wo  = (const float*)d_in[7];
  const float* bo  = (const float*)d_in[8];
  const float* g1  = (const float*)d_in[9];
  const float* be1 = (const float*)d_in[10];
  const float* W1  = (const float*)d_in[11];
  const float* b1  = (const float*)d_in[12];
  const float* W2  = (const float*)d_in[13];
  const float* b2  = (const float*)d_in[14];
  const float* g2  = (const float*)d_in[15];
  const float* be2 = (const float*)d_in[16];
  float* out = (float*)d_out;

  char* w = (char*)d_ws;
  u16* wqkv = (u16*)w; w += (size_t)3072 * 1024 * 2;   // contiguous bf16 weights:
  u16* wob  = (u16*)w; w += (size_t)1024 * 1024 * 2;   //   wqkv|wob|w1b|w2b
  u16* w1b  = (u16*)w; w += (size_t)4096 * 1024 * 2;
  u16* w2b  = (u16*)w; w += (size_t)1024 * 4096 * 2;
  u16* hb   = (u16*)w; w += (size_t)4096 * 1024 * 2;
  u16* qb   = (u16*)w; w += (size_t)4096 * 1024 * 2;   // later: MLP2 partials (4x8MB
  u16* kb   = (u16*)w; w += (size_t)4096 * 1024 * 2;   //   bf16 spanning qb..atb)
  u16* vtb  = (u16*)w; w += (size_t)4096 * 1024 * 2;
  u16* atb  = (u16*)w; w += (size_t)4096 * 1024 * 2;
  u16* m1b  = (u16*)w; w += (size_t)4096 * 4096 * 2;   // O-proj partials first (2x8MB)

  u16* op_part = m1b;   // O-proj bf16 partials, dead before MLP1 writes m1b
  u16* ml_part = qb;    // MLP2 bf16 partials, qb..atb all dead after O-proj

  f2b_all<<<12288, 256, 0, stream>>>(Wq, Wk, Wv, Wo, W1, W2, wqkv);

  ln_kernel<<<4096, 256, 0, stream>>>(x, g1, be1, hb);
  // QKV: M=4096, N=3072, K=1024 -> grid 16*24 = 384
  gemm_bt<EpiQKV><<<384, 256, 0, stream>>>(hb, wqkv, 1024, 1024, 24,
      EpiQKV{qb, kb, vtb, bq, bk, bv});
  attn_kernel<<<dim3(16, 16, 2), 256, 0, stream>>>(qb, kb, vtb, atb);
  // O-proj: N=1024, K=1024 split 2 -> grid 16*8*2 = 256
  gemm_bt<EpiPartB><<<256, 256, 0, stream>>>(atb, wob, 1024, 512, 8,
      EpiPartB{op_part});
  ln_fuse<<<4096, 256, 0, stream>>>(x, op_part, bo, g2, be2, out, hb);
  // MLP1: N=4096, K=1024 -> grid 16*32 = 512
  gemm_bt<EpiGelu><<<512, 256, 0, stream>>>(hb, w1b, 1024, 1024, 32,
      EpiGelu{b1, m1b});
  // MLP2: N=1024, K=4096 split 4 -> grid 16*8*4 = 512
  gemm_bt<EpiPartB><<<512, 256, 0, stream>>>(m1b, w2b, 4096, 1024, 8,
      EpiPartB{ml_part});
  add4<<<4096, 256, 0, stream>>>(out, ml_part, b2);
}

// Round 15
// 331.257 us; speedup vs baseline: 1.0524x; 1.0255x over previous
//
#include <hip/hip_runtime.h>

typedef unsigned short u16;
typedef __attribute__((ext_vector_type(8))) __bf16 bf16x8;
typedef __attribute__((ext_vector_type(4))) __bf16 bf16x4;
typedef __attribute__((ext_vector_type(4))) float f32x4;
typedef __attribute__((ext_vector_type(4))) unsigned short u16x4;

#define AS1 __attribute__((address_space(1)))
#define AS3 __attribute__((address_space(3)))

__device__ __forceinline__ void async_load16(const void* g, void* l) {
  __builtin_amdgcn_global_load_lds((const AS1 void*)g, (AS3 void*)l, 16, 0, 0);
}

__device__ __forceinline__ float exp2_fast(float x) {
#if __has_builtin(__builtin_amdgcn_exp2f)
  return __builtin_amdgcn_exp2f(x);
#else
  return exp2f(x);
#endif
}
__device__ __forceinline__ float rcp_fast(float x) {
#if __has_builtin(__builtin_amdgcn_rcpf)
  return __builtin_amdgcn_rcpf(x);
#else
  return 1.0f / x;
#endif
}

__device__ __forceinline__ u16 f2bf(float f) {   // manual RNE
  union { float f; unsigned u; } a; a.f = f;
  unsigned u = a.u;
  u += 0x7fffu + ((u >> 16) & 1u);
  return (u16)(u >> 16);
}
__device__ __forceinline__ u16 bf_bits(float f) {  // native cvt (RNE)
  union { __bf16 b; u16 u; } c; c.b = (__bf16)f; return c.u;
}
__device__ __forceinline__ float bf2f(u16 h) {
  union { unsigned u; float f; } c; c.u = ((unsigned)h) << 16; return c.f;
}

// ------- merged: fp32->bf16 weight convert (blocks 4096..16383) + LayerNorm
// (blocks 0..4095). Independent work, both BW-bound; one launch overlaps the
// streams and saves a launch gap. Branch is block-uniform (barrier-safe).
// NOTE: LN locals named sum/sq to avoid shadowing weight params s0..s5 (R14
// compile failure: local "s2" resolved to the Wv pointer parameter). -------
__global__ __launch_bounds__(256)
void f2b_ln(const float* __restrict__ s0, const float* __restrict__ s1,
            const float* __restrict__ s2, const float* __restrict__ s3,
            const float* __restrict__ s4, const float* __restrict__ s5,
            u16* __restrict__ dst,
            const float* __restrict__ x, const float* __restrict__ g,
            const float* __restrict__ b, u16* __restrict__ out) {
  const int tid = threadIdx.x;
  if (blockIdx.x >= 4096) {            // ---- weight convert ----
    const int i = (blockIdx.x - 4096) * 256 + tid;   // < 3145728
    const float* src; int off;
    if (i < 1048576) {
      if (i < 262144)      { src = s0; off = i; }
      else if (i < 524288) { src = s1; off = i - 262144; }
      else if (i < 786432) { src = s2; off = i - 524288; }
      else                 { src = s3; off = i - 786432; }
    } else if (i < 2097152) { src = s4; off = i - 1048576; }
    else                    { src = s5; off = i - 2097152; }
    const float4 v = ((const float4*)src)[off];
    u16x4 o; o[0] = f2bf(v.x); o[1] = f2bf(v.y); o[2] = f2bf(v.z); o[3] = f2bf(v.w);
    ((u16x4*)dst)[i] = o;
    return;
  }
  // ---- LayerNorm row ----
  const int row = blockIdx.x;
  const float4 v = ((const float4*)(x + (size_t)row * 1024))[tid];
  float sum = v.x + v.y + v.z + v.w;
  float sq = v.x * v.x + v.y * v.y + v.z * v.z + v.w * v.w;
#pragma unroll
  for (int o = 1; o < 64; o <<= 1) { sum += __shfl_xor(sum, o); sq += __shfl_xor(sq, o); }
  __shared__ float red[8];
  const int wave = tid >> 6, lane = tid & 63;
  if (lane == 0) { red[wave] = sum; red[wave + 4] = sq; }
  __syncthreads();
  sum = red[0] + red[1] + red[2] + red[3];
  sq = red[4] + red[5] + red[6] + red[7];
  const float mu = sum * (1.f / 1024.f);
  const float rstd = rsqrtf(sq * (1.f / 1024.f) - mu * mu + 1e-5f);
  const float4 gg = ((const float4*)g)[tid];
  const float4 bb = ((const float4*)b)[tid];
  u16x4 o4;
  o4[0] = f2bf((v.x - mu) * rstd * gg.x + bb.x);
  o4[1] = f2bf((v.y - mu) * rstd * gg.y + bb.y);
  o4[2] = f2bf((v.z - mu) * rstd * gg.z + bb.z);
  o4[3] = f2bf((v.w - mu) * rstd * gg.w + bb.w);
  ((u16x4*)(out + (size_t)row * 1024))[tid] = o4;
}

// -- fused: out = x + p[0..3] + bo (bf16 partials); hb = LN(out; g,b) --
__global__ __launch_bounds__(256)
void ln_fuse(const float* __restrict__ x, const u16* __restrict__ parts,
             const float* __restrict__ bo, const float* __restrict__ g,
             const float* __restrict__ b, float* __restrict__ out,
             u16* __restrict__ hb) {
  const int row = blockIdx.x, tid = threadIdx.x;
  const size_t base = (size_t)row * 1024;
  const int i4 = row * 256 + tid;
  const float4 xv = ((const float4*)(x + base))[tid];
  const float4 bv = ((const float4*)bo)[tid];
  float4 t;
  t.x = xv.x + bv.x; t.y = xv.y + bv.y; t.z = xv.z + bv.z; t.w = xv.w + bv.w;
#pragma unroll
  for (int kz = 0; kz < 4; kz++) {
    const u16x4 h = ((const u16x4*)(parts + (size_t)kz * 4194304))[i4];
    t.x += bf2f(h[0]); t.y += bf2f(h[1]); t.z += bf2f(h[2]); t.w += bf2f(h[3]);
  }
  ((float4*)(out + base))[tid] = t;
  float s = t.x + t.y + t.z + t.w;
  float s2 = t.x * t.x + t.y * t.y + t.z * t.z + t.w * t.w;
#pragma unroll
  for (int o = 1; o < 64; o <<= 1) { s += __shfl_xor(s, o); s2 += __shfl_xor(s2, o); }
  __shared__ float red[8];
  const int wave = tid >> 6, lane = tid & 63;
  if (lane == 0) { red[wave] = s; red[wave + 4] = s2; }
  __syncthreads();
  s = red[0] + red[1] + red[2] + red[3];
  s2 = red[4] + red[5] + red[6] + red[7];
  const float mu = s * (1.f / 1024.f);
  const float rstd = rsqrtf(s2 * (1.f / 1024.f) - mu * mu + 1e-5f);
  const float4 gg = ((const float4*)g)[tid];
  const float4 bb = ((const float4*)b)[tid];
  u16x4 o4;
  o4[0] = f2bf((t.x - mu) * rstd * gg.x + bb.x);
  o4[1] = f2bf((t.y - mu) * rstd * gg.y + bb.y);
  o4[2] = f2bf((t.z - mu) * rstd * gg.z + bb.z);
  o4[3] = f2bf((t.w - mu) * rstd * gg.w + bb.w);
  ((u16x4*)(hb + base))[tid] = o4;
}

// ------- out += p[0..3] + b2 (MLP2 reduction over 4 bf16 partial slices) -------
__global__ __launch_bounds__(256)
void add4(float* __restrict__ out, const u16* __restrict__ p,
          const float* __restrict__ b2) {
  const int i = blockIdx.x * 256 + threadIdx.x;   // f4 index < 1048576
  const float4 o = ((const float4*)out)[i];
  const float4 bv = ((const float4*)b2)[i & 255];
  float a0 = o.x + bv.x, a1 = o.y + bv.y, a2 = o.z + bv.z, a3 = o.w + bv.w;
#pragma unroll
  for (int kz = 0; kz < 4; kz++) {
    const u16x4 h = ((const u16x4*)(p + (size_t)kz * 4194304))[i];
    a0 += bf2f(h[0]); a1 += bf2f(h[1]); a2 += bf2f(h[2]); a3 += bf2f(h[3]);
  }
  float4 r; r.x = a0; r.y = a1; r.z = a2; r.w = a3;
  ((float4*)out)[i] = r;
}

// ---------------- GEMM C = A * B^T, A[M,ldk] bf16, B[N,ldk] bf16 ----------------
// R6-proven form: BM=256, BN=128, BK=64; 4 waves, wave tile 64x128 (acc 4x8).
// 2-barrier structure; m201-exact st_16x32 swizzle (chunk-bit1 ^= row-bit2)
// staged via pre-swizzled global src (dest wave-uniform linear, m104/m108).
template <class Epi>
__global__ __launch_bounds__(256, 2)
void gemm_bt(const u16* __restrict__ A, const u16* __restrict__ Bw,
             int ldk, int K, int NB, Epi epi) {
  __shared__ __align__(16) u16 As[256 * 64];   // 32 KB
  __shared__ __align__(16) u16 Bs[128 * 64];   // 16 KB
  const int tid = threadIdx.x;
  const int wave = tid >> 6, lane = tid & 63;
  const int quad = lane >> 4, l16 = lane & 15;
  const int id = blockIdx.x;
  const int mb = id & 15;
  const int t = id >> 4;
  const int nb = t % NB;
  const int kz = t / NB;
  const int bm = mb * 256, bn = nb * 128;
  const int wm = wave * 64;

  const int srow = lane >> 3;                 // 0..7 (row within 8-row block)
  const int chunk = lane & 7;                 // 16B chunk slot this lane fills
  const int scol = (chunk ^ (2 * ((srow >> 2) & 1))) * 8;  // inverse-swizzled src
  const u16* pa[8];
  u16* la[8];
#pragma unroll
  for (int j = 0; j < 8; j++) {
    pa[j] = A + (size_t)(bm + wave * 64 + j * 8 + srow) * ldk + (size_t)kz * K + scol;
    la[j] = &As[wave * 4096 + j * 512];       // wave-uniform dest
  }
  const u16* pb[4];
  u16* lb[4];
#pragma unroll
  for (int j = 0; j < 4; j++) {
    pb[j] = Bw + (size_t)(bn + wave * 32 + j * 8 + srow) * ldk + (size_t)kz * K + scol;
    lb[j] = &Bs[wave * 2048 + j * 512];
  }

  const f32x4 fz = {0.f, 0.f, 0.f, 0.f};
  f32x4 acc[4][8];
#pragma unroll
  for (int i = 0; i < 4; i++)
#pragma unroll
    for (int j = 0; j < 8; j++) acc[i][j] = fz;

  const int qsw = (quad ^ (2 * ((l16 >> 2) & 1))) * 8;  // swizzled 16B slot

  for (int k0 = 0; k0 < K; k0 += 64) {
#pragma unroll
    for (int j = 0; j < 8; j++) { async_load16(pa[j], la[j]); pa[j] += 64; }
#pragma unroll
    for (int j = 0; j < 4; j++) { async_load16(pb[j], lb[j]); pb[j] += 64; }
    __syncthreads();
#pragma unroll
    for (int kk = 0; kk < 2; kk++) {
      const int slot = qsw + kk * 32;
      bf16x8 af[4], bfr[8];
#pragma unroll
      for (int mi = 0; mi < 4; mi++)
        af[mi] = *(const bf16x8*)&As[(wm + mi * 16 + l16) * 64 + slot];
#pragma unroll
      for (int ni = 0; ni < 8; ni++)
        bfr[ni] = *(const bf16x8*)&Bs[(ni * 16 + l16) * 64 + slot];
#pragma unroll
      for (int mi = 0; mi < 4; mi++)
#pragma unroll
        for (int ni = 0; ni < 8; ni++)
          acc[mi][ni] = __builtin_amdgcn_mfma_f32_16x16x32_bf16(af[mi], bfr[ni], acc[mi][ni], 0, 0, 0);
    }
    __syncthreads();
  }
#pragma unroll
  for (int mi = 0; mi < 4; mi++)
#pragma unroll
    for (int ni = 0; ni < 8; ni++)
      epi(bm + wm + mi * 16 + quad * 4, bn + ni * 16 + l16, kz, acc[mi][ni]);
}

// ---------------- epilogues (rows m0..m0+3, col n) ----------------
struct EpiQKV {   // q[b,h,s,e] scaled by 0.125*log2(e); k[b,h,s,e]; v^T[b,h,e,s]
  u16 *q, *k, *vt; const float *bq, *bk, *bv;
  __device__ void operator()(int m0, int n, int, f32x4 v) const {
    const int which = n >> 10, nn = n & 1023;
    const int hh = nn >> 6, e = nn & 63;
    const int bb = m0 >> 11, s0 = m0 & 2047;
    const size_t bh = (size_t)(bb * 16 + hh);
    if (which == 0) {
      const float bias = bq[nn];
      u16* p = &q[(bh * 2048 + s0) * 64 + e];
#pragma unroll
      for (int r = 0; r < 4; r++) p[r * 64] = bf_bits((v[r] + bias) * 0.18033688f);
    } else if (which == 1) {
      const float bias = bk[nn];
      u16* p = &k[(bh * 2048 + s0) * 64 + e];
#pragma unroll
      for (int r = 0; r < 4; r++) p[r * 64] = bf_bits(v[r] + bias);
    } else {
      const float bias = bv[nn];
      bf16x4 pk;
#pragma unroll
      for (int r = 0; r < 4; r++) pk[r] = (__bf16)(v[r] + bias);
      *(bf16x4*)&vt[(bh * 64 + e) * 2048 + s0] = pk;
    }
  }
};
struct EpiPartB {  // bf16 split-K partial -> p + kz*4194304  ([4096,1024] bf16)
  u16* p;
  __device__ void operator()(int m0, int n, int kz, f32x4 v) const {
    u16* pp = p + (size_t)kz * 4194304;
#pragma unroll
    for (int r = 0; r < 4; r++) pp[(size_t)(m0 + r) * 1024 + n] = bf_bits(v[r]);
  }
};
struct EpiGelu {  // gelu(u) = u * sigmoid(2*c*(u+0.044715u^3)) via exp2
  const float* b1; u16* o;
  __device__ void operator()(int m0, int n, int, f32x4 v) const {
    const float bias = b1[n];
#pragma unroll
    for (int r = 0; r < 4; r++) {
      const float u = v[r] + bias;
      const float z2 = u * (2.3021183f + 0.10294515f * u * u);
      const float d = 1.0f + exp2_fast(-z2);
      o[(size_t)(m0 + r) * 4096 + n] = bf_bits(u * rcp_fast(d));
    }
  }
};

// ---------------- flash attention, no-max softmax, KVBLK=128, 1 wave = 32 q-rows ----
// R6-proven form. K LDS rows permuted (row u holds K[kv = 8*(u&15)+(u>>4)]) so
// the P tile lands in true-kv order as contiguous bf16x8 stores; V^T unpermuted.
__global__ __launch_bounds__(256)
void attn_kernel(const u16* __restrict__ Q, const u16* __restrict__ K,
                 const u16* __restrict__ Vt, u16* __restrict__ O) {
  __shared__ __align__(16) u16 Ks[128 * 72];    // 18.4 KB (K rows, 64 d + pad)
  __shared__ __align__(16) u16 Vs[64 * 136];    // 17.4 KB (e rows, 128 s + pad)
  __shared__ __align__(16) u16 Ps[4][32 * 136]; // 34.8 KB (per-wave P tiles)
  const int tid = threadIdx.x, wave = tid >> 6, lane = tid & 63;
  const int quad = lane >> 4, l16 = lane & 15;
  const int b = blockIdx.z, h = blockIdx.y, qt = blockIdx.x;
  const size_t bh = (size_t)(b * 16 + h);
  const u16* Qp = Q + bh * (size_t)(2048 * 64);
  const u16* Kp = K + bh * (size_t)(2048 * 64);
  const u16* Vp = Vt + bh * (size_t)(64 * 2048);
  const int q0 = qt * 128 + wave * 32;

  bf16x8 qf[2][2];
#pragma unroll
  for (int rg = 0; rg < 2; rg++) {
    const u16* qrow = &Qp[(size_t)(q0 + rg * 16 + l16) * 64 + quad * 8];
    qf[rg][0] = *(const bf16x8*)qrow;
    qf[rg][1] = *(const bf16x8*)(qrow + 32);
  }

  // K staging: 128 rows x 64 d / 256 thr = 32 u16/thr (half a row)
  const int srK = tid >> 1, scK = (tid & 1) * 32;
  const int krow = 8 * (srK & 15) + (srK >> 4);        // permuted key row
  const u16* kg = &Kp[(size_t)krow * 64 + scK];
  u16* kl = &Ks[srK * 72 + scK];
  // V staging: 64 e-rows x 128 s / 256 thr = 32 u16/thr
  const int srV = tid >> 2, scV = (tid & 3) * 32;
  const u16* vg = &Vp[(size_t)srV * 2048 + scV];
  u16* vl = &Vs[srV * 136 + scV];
  u16* Pw = &Ps[wave][0];

  bf16x8 ones;
#pragma unroll
  for (int i = 0; i < 8; i++) ones[i] = (__bf16)1.0f;

  const f32x4 fz = {0.f, 0.f, 0.f, 0.f};
  f32x4 acc[2][4], lsum[2];
#pragma unroll
  for (int rg = 0; rg < 2; rg++) {
    lsum[rg] = fz;
#pragma unroll
    for (int g = 0; g < 4; g++) acc[rg][g] = fz;
  }

  bf16x8 pk[4], pv[4];
#pragma unroll
  for (int c = 0; c < 4; c++) {
    pk[c] = *(const bf16x8*)(kg + 8 * c);
    pv[c] = *(const bf16x8*)(vg + 8 * c);
  }

  for (int t0 = 0; t0 < 2048; t0 += 128) {
#pragma unroll
    for (int c = 0; c < 4; c++) {
      *(bf16x8*)(kl + 8 * c) = pk[c];
      *(bf16x8*)(vl + 8 * c) = pv[c];
    }
    __syncthreads();
    kg += 128 * 64; vg += 128;
#pragma unroll
    for (int c = 0; c < 4; c++) {        // over-reads 1 tile past end: lands in
      pk[c] = *(const bf16x8*)(kg + 8 * c);   // the next ws buffer, unused
      pv[c] = *(const bf16x8*)(vg + 8 * c);
    }

    // ---- QK^T, first half (kv tiles g 0..3) ----
    f32x4 s[2][4];
    __builtin_amdgcn_s_setprio(1);
#pragma unroll
    for (int g = 0; g < 4; g++) {
      const u16* kr = &Ks[(g * 16 + l16) * 72 + quad * 8];
      const bf16x8 kb0 = *(const bf16x8*)kr;
      const bf16x8 kb1 = *(const bf16x8*)(kr + 32);
#pragma unroll
      for (int rg = 0; rg < 2; rg++) {
        f32x4 z = __builtin_amdgcn_mfma_f32_16x16x32_bf16(qf[rg][0], kb0, fz, 0, 0, 0);
        s[rg][g] = __builtin_amdgcn_mfma_f32_16x16x32_bf16(qf[rg][1], kb1, z, 0, 0, 0);
      }
    }
    __builtin_amdgcn_s_setprio(0);
#pragma unroll
    for (int rg = 0; rg < 2; rg++)
#pragma unroll
      for (int r = 0; r < 4; r++) {
        f32x4 pf;
#pragma unroll
        for (int g = 0; g < 4; g++) pf[g] = exp2_fast(s[rg][g][r]);
        const bf16x4 pb = __builtin_convertvector(pf, bf16x4);
        *(bf16x4*)&Pw[(rg * 16 + quad * 4 + r) * 136 + 8 * l16] = pb;
      }
    // ---- QK^T, second half (kv tiles g 4..7) ----
    __builtin_amdgcn_s_setprio(1);
#pragma unroll
    for (int g = 0; g < 4; g++) {
      const u16* kr = &Ks[((g + 4) * 16 + l16) * 72 + quad * 8];
      const bf16x8 kb0 = *(const bf16x8*)kr;
      const bf16x8 kb1 = *(const bf16x8*)(kr + 32);
#pragma unroll
      for (int rg = 0; rg < 2; rg++) {
        f32x4 z = __builtin_amdgcn_mfma_f32_16x16x32_bf16(qf[rg][0], kb0, fz, 0, 0, 0);
        s[rg][g] = __builtin_amdgcn_mfma_f32_16x16x32_bf16(qf[rg][1], kb1, z, 0, 0, 0);
      }
    }
    __builtin_amdgcn_s_setprio(0);
#pragma unroll
    for (int rg = 0; rg < 2; rg++)
#pragma unroll
      for (int r = 0; r < 4; r++) {
        f32x4 pf;
#pragma unroll
        for (int g = 0; g < 4; g++) pf[g] = exp2_fast(s[rg][g][r]);
        const bf16x4 pb = __builtin_convertvector(pf, bf16x4);
        *(bf16x4*)&Pw[(rg * 16 + quad * 4 + r) * 136 + 8 * l16 + 4] = pb;
      }

    // ---- P readback (true kv order) + row-sum + PV ----
    bf16x8 pa[2][4];
#pragma unroll
    for (int rg = 0; rg < 2; rg++)
#pragma unroll
      for (int hh2 = 0; hh2 < 4; hh2++) {
        pa[rg][hh2] = *(const bf16x8*)&Pw[(rg * 16 + l16) * 136 + quad * 8 + hh2 * 32];
        lsum[rg] = __builtin_amdgcn_mfma_f32_16x16x32_bf16(pa[rg][hh2], ones, lsum[rg], 0, 0, 0);
      }
    __builtin_amdgcn_s_setprio(1);
#pragma unroll
    for (int g = 0; g < 4; g++) {
      const u16* vr = &Vs[(g * 16 + l16) * 136 + quad * 8];
#pragma unroll
      for (int hh2 = 0; hh2 < 4; hh2++) {
        const bf16x8 vb = *(const bf16x8*)(vr + hh2 * 32);
#pragma unroll
        for (int rg = 0; rg < 2; rg++)
          acc[rg][g] = __builtin_amdgcn_mfma_f32_16x16x32_bf16(pa[rg][hh2], vb, acc[rg][g], 0, 0, 0);
      }
    }
    __builtin_amdgcn_s_setprio(0);
    __syncthreads();
  }
#pragma unroll
  for (int rg = 0; rg < 2; rg++)
#pragma unroll
    for (int r = 0; r < 4; r++) {
      const float inv = rcp_fast(lsum[rg][r]);
      const int s_row = q0 + rg * 16 + quad * 4 + r;
      u16* op = (u16*)&O[((size_t)(b * 2048 + s_row)) * 1024 + h * 64 + l16];
#pragma unroll
      for (int g = 0; g < 4; g++) op[g * 16] = bf_bits(acc[rg][g][r] * inv);
    }
}

// ---------------- launch ----------------
extern "C" void kernel_launch(void* const* d_in, const int* in_sizes, int n_in,
                              void* d_out, int out_size, void* d_ws, size_t ws_size,
                              hipStream_t stream) {
  const float* x   = (const float*)d_in[0];
  const float* Wq  = (const float*)d_in[1];
  const float* bq  = (const float*)d_in[2];
  const float* Wk  = (const float*)d_in[3];
  const float* bk  = (const float*)d_in[4];
  const float* Wv  = (const float*)d_in[5];
  const float* bv  = (const float*)d_in[6];
  const float* Wo  = (const float*)d_in[7];
  const float* bo  = (const float*)d_in[8];
  const float* g1  = (const float*)d_in[9];
  const float* be1 = (const float*)d_in[10];
  const float* W1  = (const float*)d_in[11];
  const float* b1  = (const float*)d_in[12];
  const float* W2  = (const float*)d_in[13];
  const float* b2  = (const float*)d_in[14];
  const float* g2  = (const float*)d_in[15];
  const float* be2 = (const float*)d_in[16];
  float* out = (float*)d_out;

  char* w = (char*)d_ws;
  u16* wqkv = (u16*)w; w += (size_t)3072 * 1024 * 2;   // contiguous bf16 weights:
  u16* wob  = (u16*)w; w += (size_t)1024 * 1024 * 2;   //   wqkv|wob|w1b|w2b
  u16* w1b  = (u16*)w; w += (size_t)4096 * 1024 * 2;
  u16* w2b  = (u16*)w; w += (size_t)1024 * 4096 * 2;
  u16* hb   = (u16*)w; w += (size_t)4096 * 1024 * 2;
  u16* qb   = (u16*)w; w += (size_t)4096 * 1024 * 2;   // later: MLP2 partials (4x8MB
  u16* kb   = (u16*)w; w += (size_t)4096 * 1024 * 2;   //   bf16 spanning qb..atb)
  u16* vtb  = (u16*)w; w += (size_t)4096 * 1024 * 2;
  u16* atb  = (u16*)w; w += (size_t)4096 * 1024 * 2;
  u16* m1b  = (u16*)w; w += (size_t)4096 * 4096 * 2;   // O-proj partials first (4x8MB)

  u16* op_part = m1b;   // O-proj bf16 partials, dead before MLP1 writes m1b
  u16* ml_part = qb;    // MLP2 bf16 partials, qb..atb all dead after O-proj

  // merged weight-convert + LN1 (blocks 0..4095 = LN, 4096..16383 = convert)
  f2b_ln<<<16384, 256, 0, stream>>>(Wq, Wk, Wv, Wo, W1, W2, wqkv, x, g1, be1, hb);
  // QKV: M=4096, N=3072, K=1024 -> grid 16*24 = 384
  gemm_bt<EpiQKV><<<384, 256, 0, stream>>>(hb, wqkv, 1024, 1024, 24,
      EpiQKV{qb, kb, vtb, bq, bk, bv});
  attn_kernel<<<dim3(16, 16, 2), 256, 0, stream>>>(qb, kb, vtb, atb);
  // O-proj: N=1024, K=1024 split 4 -> grid 16*8*4 = 512 (2 blocks/CU)
  gemm_bt<EpiPartB><<<512, 256, 0, stream>>>(atb, wob, 1024, 256, 8,
      EpiPartB{op_part});
  ln_fuse<<<4096, 256, 0, stream>>>(x, op_part, bo, g2, be2, out, hb);
  // MLP1: N=4096, K=1024 -> grid 16*32 = 512
  gemm_bt<EpiGelu><<<512, 256, 0, stream>>>(hb, w1b, 1024, 1024, 32,
      EpiGelu{b1, m1b});
  // MLP2: N=1024, K=4096 split 4 -> grid 16*8*4 = 512
  gemm_bt<EpiPartB><<<512, 256, 0, stream>>>(m1b, w2b, 4096, 1024, 8,
      EpiPartB{ml_part});
  add4<<<4096, 256, 0, stream>>>(out, ml_part, b2);
}